// Round 13
// baseline (594.095 us; speedup 1.0000x reference)
//
#include <hip/hip_runtime.h>
#include <math.h>

typedef unsigned int u32;
typedef __attribute__((ext_vector_type(8))) short bf16x8;
typedef __attribute__((ext_vector_type(4))) float f32x4;

#define MFMA16(a,b,c) __builtin_amdgcn_mfma_f32_16x16x32_bf16(a,b,c,0,0,0)

// ---------- bf16 helpers ----------
__device__ inline u32 bf16r(float x){
  u32 u = __float_as_uint(x);
  return (u + 0x7fffu + ((u >> 16) & 1u)) >> 16;
}
__device__ inline u32 pack2(float a, float b){ return bf16r(a) | (bf16r(b) << 16); }
__device__ inline uint4 pack8(const float* f){
  uint4 v; v.x = pack2(f[0],f[1]); v.y = pack2(f[2],f[3]);
  v.z = pack2(f[4],f[5]); v.w = pack2(f[6],f[7]); return v;
}
__device__ inline float bf2f(short s){ return __uint_as_float(((u32)(unsigned short)s) << 16); }

// async global->LDS, 16B/lane; dest = wave-uniform base + lane*16 (src per-lane OK)
__device__ __forceinline__ void gload_lds16(const void* g, void* l){
  __builtin_amdgcn_global_load_lds((const __attribute__((address_space(1))) unsigned int*)g,
                                   (__attribute__((address_space(3))) unsigned int*)l,
                                   16, 0, 0);
}

// LDS fragment offset (shorts) in paired-macro-row granule layout
__device__ __forceinline__ int frag_off(int f, int quad){
  return (f>>1)*64 + (f&1)*32 + ((quad ^ ((f>>1)&3))*8);
}

// xls float4-granule swizzle (verified conflict-free for self/neighbor/residual patterns)
__device__ __forceinline__ int xg(int g, int r){ return g ^ ((r ^ (g>>3)) & 7); }

// ---------- merged weight converter: f32 [K][Nf] -> bf16 row-major [Nf][K] ----------
__global__ void k_cvtAll(const float* __restrict__ inW2, const float* __restrict__ gW1,
                         const float* __restrict__ gW2, const float* __restrict__ oW1,
                         const float* __restrict__ oW2,
                         short* __restrict__ w2t, short* __restrict__ gw1t,
                         short* __restrict__ gw2t, short* __restrict__ ow1t,
                         short* __restrict__ ow2t){
  int gidx = blockIdx.x*256 + threadIdx.x;
  const float* src; short* dst; int t, K8, Nf;
  if (gidx < 8192)      { src = inW2; dst = w2t; t = gidx; K8 = 32; Nf = 256; }
  else if (gidx < 40960){ int r = gidx-8192;  int c = r>>13; t = r&8191;
                          src = gW1 + (size_t)c*65536; dst = gw1t + (size_t)c*65536; K8 = 32; Nf = 256; }
  else if (gidx < 73728){ int r = gidx-40960; int c = r>>13; t = r&8191;
                          src = gW2 + (size_t)c*65536; dst = gw2t + (size_t)c*65536; K8 = 32; Nf = 256; }
  else if (gidx < 90112){ t = gidx-73728; src = oW1; dst = ow1t; K8 = 64; Nf = 256; }
  else if (gidx < 94208){ t = gidx-90112; src = oW2; dst = ow2t; K8 = 32; Nf = 128; }
  else return;
  int f = t / K8, c = t - f*K8;
  float v[8];
  #pragma unroll
  for (int j=0;j<8;j++) v[j] = src[(size_t)(c*8+j)*Nf + f];
  ((uint4*)dst)[t] = pack8(v);
}

// ---------- per-edge scalars + CSR in-edge lists ----------
__global__ void k_pre(const int* __restrict__ ei, const int* __restrict__ n2g,
                      const int* __restrict__ nl, const float* __restrict__ sigmas,
                      const float* __restrict__ pos, const float* __restrict__ dn, int E,
                      float* __restrict__ pd, int* __restrict__ cnt, int* __restrict__ inlist){
  int e = blockIdx.x*256 + threadIdx.x;
  if (e >= E) return;
  int r = ei[e], c = ei[E+e];
  float sg = sigmas[nl[n2g[r]]];
  float dx = pos[3*r]-pos[3*c], dy = pos[3*r+1]-pos[3*c+1], dz = pos[3*r+2]-pos[3*c+2];
  float d = sqrtf(dx*dx + dy*dy + dz*dz);
  pd[e] = d + dn[e]*sg;
  int slot = atomicAdd(&cnt[c], 1);
  if (slot < 8) inlist[c*8 + slot] = e;
}

// ---------- edge_attr: barrier-free, no LDS. B computed in registers ----------
__global__ __launch_bounds__(256) void k_attr(
    const float* __restrict__ pd, const float* __restrict__ W1, const float* __restrict__ b1,
    const short* __restrict__ W2t, const float* __restrict__ b2,
    const int* __restrict__ etype, const float* __restrict__ eemb,
    short* __restrict__ attr, int E)
{
  int tid = threadIdx.x;
  int base = blockIdx.x*64;
  int wv = tid>>6, lane = tid&63, quad = lane>>4, l15 = lane&15;
  float pdv[4];
  #pragma unroll
  for (int nt=0;nt<4;nt++) pdv[nt] = pd[base + nt*16 + l15];
  f32x4 acc[4][4];
  #pragma unroll
  for (int mt=0;mt<4;mt++) for (int nt=0;nt<4;nt++) acc[mt][nt] = (f32x4)0.f;
  #pragma unroll
  for (int s=0; s<8; s++){
    int k0 = s*32 + quad*8;
    float4 w1a = *(const float4*)(W1 + k0), w1b = *(const float4*)(W1 + k0 + 4);
    float4 b1a = *(const float4*)(b1 + k0), b1b = *(const float4*)(b1 + k0 + 4);
    bf16x8 a[4], b[4];
    #pragma unroll
    for (int mt=0;mt<4;mt++){
      int f = (wv*4+mt)*16 + l15;
      a[mt] = *(const bf16x8*)(W2t + (size_t)f*256 + k0);
    }
    #pragma unroll
    for (int nt=0;nt<4;nt++){
      float p = pdv[nt];
      float f[8] = {fmaxf(p*w1a.x+b1a.x,0.f), fmaxf(p*w1a.y+b1a.y,0.f),
                    fmaxf(p*w1a.z+b1a.z,0.f), fmaxf(p*w1a.w+b1a.w,0.f),
                    fmaxf(p*w1b.x+b1b.x,0.f), fmaxf(p*w1b.y+b1b.y,0.f),
                    fmaxf(p*w1b.z+b1b.z,0.f), fmaxf(p*w1b.w+b1b.w,0.f)};
      uint4 u = pack8(f);
      b[nt] = *(bf16x8*)&u;
    }
    #pragma unroll
    for (int mt=0;mt<4;mt++)
      #pragma unroll
      for (int nt=0;nt<4;nt++)
        acc[mt][nt] = MFMA16(a[mt], b[nt], acc[mt][nt]);
  }
  #pragma unroll
  for (int nt=0;nt<4;nt++){
    int e = base + nt*16 + l15;
    int et = etype[e];
    #pragma unroll
    for (int mt=0;mt<4;mt++){
      int f0 = (wv*4+mt)*16 + quad*4;
      float4 bb = *(const float4*)(b2 + f0);
      float4 em = *(const float4*)(eemb + (size_t)et*256 + f0);
      float v0 = (acc[mt][nt][0]+bb.x)*em.x, v1 = (acc[mt][nt][1]+bb.y)*em.y;
      float v2 = (acc[mt][nt][2]+bb.z)*em.z, v3 = (acc[mt][nt][3]+bb.w)*em.w;
      uint2 v; v.x = pack2(v0,v1); v.y = pack2(v2,v3);
      *(uint2*)(attr + (size_t)e*256 + f0) = v;
    }
  }
}

// ---------- per-graph fused 4-conv kernel: x AND attr resident in LDS for all convs ----------
// 1 block = 1 graph (32 nodes, 180 edges). attr staged ONCE (92KB); zero global traffic in loop.
#define EPG 180
__global__ __launch_bounds__(256,1) void k_conv4(
    const int* __restrict__ at, const float* __restrict__ nemb,
    const short* __restrict__ attrS, const int* __restrict__ ei,
    const int* __restrict__ cnt, const int* __restrict__ inlist,
    const short* __restrict__ gw1t, const float* __restrict__ gb1,
    const short* __restrict__ gw2t, const float* __restrict__ gb2,
    short* __restrict__ xF)
{
  __shared__ float xls[32*256];       // 32 KB
  __shared__ uint4 AlsV[32*32];       // 16 KB; T1 aliases
  __shared__ uint4 attrLV[EPG*32];    // 92160 B: [edge][256 shorts], linear
  short* Als = (short*)AlsV;
  short* T1  = Als;
  short* attrL = (short*)attrLV;
  int tid = threadIdx.x;
  int nbase = blockIdx.x*32;
  int ebase = blockIdx.x*EPG;
  int wv = tid>>6, lane = tid&63, quad = lane>>4, l15 = lane&15;
  int jl = tid>>3, ch = tid&7;
  // ---- stage attr for this graph: 92160 B contiguous, 90 x 1024B chunks ----
  {
    const char* src = (const char*)(attrS + (size_t)ebase*256) + lane*16;
    char* dst = (char*)attrLV;
    #pragma unroll
    for (int i=0; i<23; i++){
      int r = i*4 + wv;
      if (r < 90) gload_lds16(src + r*1024, dst + r*1024);
    }
  }
  // ---- hoist in-edge topology into registers (local edge ids) ----
  int deg, eid[8], rl[8];
  {
    int j = nbase + jl;
    deg = min(cnt[j], 8);
    #pragma unroll
    for (int s=0;s<8;s++){
      eid[s] = (s < deg) ? (inlist[j*8 + s] - ebase) : 0;
      rl[s]  = (s < deg) ? (ei[ebase + eid[s]] - nbase) : 0;
    }
  }
  // ---- init xls from node_emb[at] ----
  {
    int a = at[nbase + jl];
    const float4* src = (const float4*)nemb + (size_t)a*64 + ch*8;
    float* xrow = xls + jl*256;
    #pragma unroll
    for (int q=0;q<8;q++)
      *(float4*)(xrow + (xg(ch*8+q, jl)<<2)) = src[q];
  }
  __syncthreads();   // drains gloads (vmcnt) + ds writes
  for (int c=0; c<4; c++){
    const short* W1t = gw1t + (size_t)c*65536;
    const short* W2t = gw2t + (size_t)c*65536;
    const float* b1 = gb1 + c*256;
    const float* b2 = gb2 + c*256;
    // ---- gather staging into Als (bf16): hin[j] = x[j] + sum relu(x[r]+attr[e]) ----
    {
      float f[32];
      const float* xrow = xls + jl*256;
      #pragma unroll
      for (int q=0;q<8;q++){
        float4 v = *(const float4*)(xrow + (xg(ch*8+q, jl)<<2));
        f[q*4]=v.x; f[q*4+1]=v.y; f[q*4+2]=v.z; f[q*4+3]=v.w;
      }
      for (int sIt=0; sIt<deg; sIt++){
        int r = rl[sIt];
        const float* xr = xls + r*256;
        const short* ar = attrL + eid[sIt]*256 + ch*32;
        #pragma unroll
        for (int q=0;q<8;q++){
          float4 xv = *(const float4*)(xr + (xg(ch*8+q, r)<<2));
          u32 lo = *(const u32*)(ar + q*4);
          u32 hi = *(const u32*)(ar + q*4 + 2);
          f[q*4]   += fmaxf(xv.x + __uint_as_float(lo<<16), 0.f);
          f[q*4+1] += fmaxf(xv.y + __uint_as_float(lo&0xffff0000u), 0.f);
          f[q*4+2] += fmaxf(xv.z + __uint_as_float(hi<<16), 0.f);
          f[q*4+3] += fmaxf(xv.w + __uint_as_float(hi&0xffff0000u), 0.f);
        }
      }
      #pragma unroll
      for (int qq=0;qq<4;qq++)
        *(uint4*)(Als + jl*256 + (((ch*4+qq) ^ (jl&7))*8)) = pack8(f + qq*8);
    }
    __syncthreads();
    // ---- GEMM1: M=256 (wave owns 64 feats), N=32, K=256; A direct from L2 ----
    f32x4 acc[4][2];
    #pragma unroll
    for (int mt=0;mt<4;mt++) for (int nt=0;nt<2;nt++) acc[mt][nt] = (f32x4)0.f;
    #pragma unroll
    for (int s=0; s<8; s++){
      bf16x8 a[4], b[2];
      #pragma unroll
      for (int mt=0;mt<4;mt++)
        a[mt] = *(const bf16x8*)(W1t + (size_t)((wv*4+mt)*16 + l15)*256 + s*32 + quad*8);
      #pragma unroll
      for (int nt=0;nt<2;nt++){
        int n = nt*16 + l15; int cc = s*4 + quad;
        b[nt] = *(const bf16x8*)(Als + n*256 + ((cc ^ (n&7))*8));
      }
      #pragma unroll
      for (int mt=0;mt<4;mt++)
        #pragma unroll
        for (int nt=0;nt<2;nt++)
          acc[mt][nt] = MFMA16(a[mt], b[nt], acc[mt][nt]);
    }
    __syncthreads();   // all waves done reading Als; T1 aliases it
    #pragma unroll
    for (int mt=0;mt<4;mt++){
      int f0 = (wv*4+mt)*16 + quad*4;
      float4 bb = *(const float4*)(b1 + f0);
      int cg = f0 >> 3, off = (quad&1)*4;
      #pragma unroll
      for (int nt=0;nt<2;nt++){
        int n = nt*16 + l15;
        float v0 = fmaxf(acc[mt][nt][0]+bb.x,0.f), v1 = fmaxf(acc[mt][nt][1]+bb.y,0.f);
        float v2 = fmaxf(acc[mt][nt][2]+bb.z,0.f), v3 = fmaxf(acc[mt][nt][3]+bb.w,0.f);
        uint2 v; v.x = pack2(v0,v1); v.y = pack2(v2,v3);
        *(uint2*)(T1 + n*256 + ((cg ^ (n&7))*8) + off) = v;
      }
    }
    __syncthreads();
    // ---- GEMM2 ----
    f32x4 acc2[4][2];
    #pragma unroll
    for (int mt=0;mt<4;mt++) for (int nt=0;nt<2;nt++) acc2[mt][nt] = (f32x4)0.f;
    #pragma unroll
    for (int s=0; s<8; s++){
      bf16x8 a[4], b[2];
      #pragma unroll
      for (int mt=0;mt<4;mt++)
        a[mt] = *(const bf16x8*)(W2t + (size_t)((wv*4+mt)*16 + l15)*256 + s*32 + quad*8);
      #pragma unroll
      for (int nt=0;nt<2;nt++){
        int n = nt*16 + l15; int cc = s*4 + quad;
        b[nt] = *(const bf16x8*)(T1 + n*256 + ((cc ^ (n&7))*8));
      }
      #pragma unroll
      for (int mt=0;mt<4;mt++)
        #pragma unroll
        for (int nt=0;nt<2;nt++)
          acc2[mt][nt] = MFMA16(a[mt], b[nt], acc2[mt][nt]);
    }
    // ---- residual update into xls (relu for c<3) ----
    #pragma unroll
    for (int mt=0;mt<4;mt++){
      int f0 = (wv*4+mt)*16 + quad*4;
      float4 bb = *(const float4*)(b2 + f0);
      int g = f0 >> 2;
      #pragma unroll
      for (int nt=0;nt<2;nt++){
        int n = nt*16 + l15;
        float* px = xls + n*256 + (xg(g, n)<<2);
        float4 xv = *(float4*)px;
        float h0 = acc2[mt][nt][0]+bb.x, h1 = acc2[mt][nt][1]+bb.y;
        float h2 = acc2[mt][nt][2]+bb.z, h3 = acc2[mt][nt][3]+bb.w;
        if (c < 3){ h0=fmaxf(h0,0.f); h1=fmaxf(h1,0.f); h2=fmaxf(h2,0.f); h3=fmaxf(h3,0.f); }
        xv.x += h0; xv.y += h1; xv.z += h2; xv.w += h3;
        *(float4*)px = xv;
      }
    }
    __syncthreads();   // xls updates visible before next gather / writeout
  }
  // ---- writeout xF (bf16, row-major) ----
  {
    const float* xrow = xls + jl*256;
    float f[32];
    #pragma unroll
    for (int q=0;q<8;q++){
      float4 v = *(const float4*)(xrow + (xg(ch*8+q, jl)<<2));
      f[q*4]=v.x; f[q*4+1]=v.y; f[q*4+2]=v.z; f[q*4+3]=v.w;
    }
    #pragma unroll
    for (int qq=0;qq<4;qq++)
      *(uint4*)(xF + (size_t)(nbase+jl)*256 + ch*32 + qq*8) = pack8(f + qq*8);
  }
}

// ---------- fully fused head: L1 GEMM -> T(LDS) -> L2 GEMM -> L3 dot -> loss reduce ----------
// 64 edges/block; x is bf16; 2 global atomics/block
__global__ __launch_bounds__(256,2) void k_head(
    const short* __restrict__ xF, const short* __restrict__ attrS,
    const int* __restrict__ ei,
    const short* __restrict__ W1t, const float* __restrict__ ob1,
    const short* __restrict__ W2t, const float* __restrict__ ob2,
    const float* __restrict__ W3, const float* __restrict__ ob3,
    const float* __restrict__ dnoise, const int* __restrict__ n2g,
    float* __restrict__ out, int E, int G)
{
  __shared__ uint4 BlsV[16*256];   // 64 KB; T (32 KB) aliases after L1
  __shared__ float Sedge[64];
  __shared__ float part[4];
  short* Bls = (short*)BlsV;
  short* T   = (short*)BlsV;
  int tid = threadIdx.x;
  int base = blockIdx.x*64;
  int wv = tid>>6, lane = tid&63, quad = lane>>4, l15 = lane&15;
  if (tid < 64) Sedge[tid] = 0.f;
  if (tid < 4) part[tid] = 0.f;
  // attr slices (s=8..15): per-lane-source gload
  {
    int g = wv*64 + lane;
    int p = g>>3, hi = (g>>2)&1, cs = g&3;
    int n = p*2 + hi, cc = cs ^ (p&3);
    const short* srcb = attrS + (size_t)(base+n)*256 + cc*8;
    #pragma unroll
    for (int s=8; s<16; s++)
      gload_lds16(srcb + (s-8)*32, (char*)Bls + (size_t)s*4096 + wv*1024);
  }
  // xr*xc slices (s=0..7), bf16 inputs
  {
    int g = tid;
    int p = g>>3, hi = (g>>2)&1, cs = g&3;
    int n = p*2 + hi, cc = cs ^ (p&3);
    int rr = ei[base+n], rc = ei[E+base+n];
    const short* xr = xF + (size_t)rr*256 + cc*8;
    const short* xc = xF + (size_t)rc*256 + cc*8;
    #pragma unroll
    for (int s=0; s<8; s++){
      bf16x8 va = *(const bf16x8*)(xr + s*32);
      bf16x8 vb = *(const bf16x8*)(xc + s*32);
      float f[8];
      #pragma unroll
      for (int j=0;j<8;j++) f[j] = bf2f(va[j])*bf2f(vb[j]);
      *(uint4*)(Bls + (size_t)s*2048 + g*8) = pack8(f);
    }
  }
  __syncthreads();
  // ---- L1: 16 barrier-free K-slices; M=256, N=64 ----
  f32x4 acc[4][4];
  #pragma unroll
  for (int mt=0;mt<4;mt++) for (int nt=0;nt<4;nt++) acc[mt][nt] = (f32x4)0.f;
  #pragma unroll
  for (int s=0; s<16; s++){
    bf16x8 a[4], b[4];
    #pragma unroll
    for (int mt=0;mt<4;mt++)
      a[mt] = *(const bf16x8*)(W1t + (size_t)((wv*4+mt)*16 + l15)*512 + s*32 + quad*8);
    #pragma unroll
    for (int nt=0;nt<4;nt++)
      b[nt] = *(const bf16x8*)(Bls + (size_t)s*2048 + frag_off(nt*16 + l15, quad));
    #pragma unroll
    for (int mt=0;mt<4;mt++)
      #pragma unroll
      for (int nt=0;nt<4;nt++)
        acc[mt][nt] = MFMA16(a[mt], b[nt], acc[mt][nt]);
  }
  __syncthreads();   // all waves done reading Bls; T aliases it
  #pragma unroll
  for (int mt=0;mt<4;mt++){
    int f0 = (wv*4+mt)*16 + quad*4;
    float4 bb = *(const float4*)(ob1 + f0);
    int c = f0 >> 3, off = (quad&1)*4;
    #pragma unroll
    for (int nt=0;nt<4;nt++){
      int n = nt*16 + l15;
      float v0 = fmaxf(acc[mt][nt][0]+bb.x,0.f), v1 = fmaxf(acc[mt][nt][1]+bb.y,0.f);
      float v2 = fmaxf(acc[mt][nt][2]+bb.z,0.f), v3 = fmaxf(acc[mt][nt][3]+bb.w,0.f);
      uint2 v; v.x = pack2(v0,v1); v.y = pack2(v2,v3);
      *(uint2*)(T + n*256 + ((c ^ (n&7))*8) + off) = v;
    }
  }
  __syncthreads();
  // ---- L2: 8 barrier-free K-slices; M=128, N=64; A direct (L2-hot) ----
  f32x4 acc2[2][4];
  #pragma unroll
  for (int mt=0;mt<2;mt++) for (int nt=0;nt<4;nt++) acc2[mt][nt] = (f32x4)0.f;
  #pragma unroll
  for (int s=0; s<8; s++){
    bf16x8 a[2], b[4];
    #pragma unroll
    for (int mt=0;mt<2;mt++)
      a[mt] = *(const bf16x8*)(W2t + (size_t)((wv*2+mt)*16 + l15)*256 + s*32 + quad*8);
    #pragma unroll
    for (int nt=0;nt<4;nt++){
      int n = nt*16 + l15; int cc = s*4 + quad;
      b[nt] = *(const bf16x8*)(T + n*256 + ((cc ^ (n&7))*8));
    }
    #pragma unroll
    for (int mt=0;mt<2;mt++)
      #pragma unroll
      for (int nt=0;nt<4;nt++)
        acc2[mt][nt] = MFMA16(a[mt], b[nt], acc2[mt][nt]);
  }
  // ---- L3 dot + cross-wave per-edge reduce ----
  float4 b2v[2], w3v[2];
  #pragma unroll
  for (int mt=0;mt<2;mt++){
    int f0 = (wv*2+mt)*16 + quad*4;
    b2v[mt] = *(const float4*)(ob2 + f0);
    w3v[mt] = *(const float4*)(W3 + f0);
  }
  #pragma unroll
  for (int nt=0;nt<4;nt++){
    float p = 0.f;
    #pragma unroll
    for (int mt=0;mt<2;mt++){
      p += fmaxf(acc2[mt][nt][0]+b2v[mt].x,0.f)*w3v[mt].x;
      p += fmaxf(acc2[mt][nt][1]+b2v[mt].y,0.f)*w3v[mt].y;
      p += fmaxf(acc2[mt][nt][2]+b2v[mt].z,0.f)*w3v[mt].z;
      p += fmaxf(acc2[mt][nt][3]+b2v[mt].w,0.f)*w3v[mt].w;
    }
    p += __shfl_xor(p, 16);
    p += __shfl_xor(p, 32);
    if (lane < 16) atomicAdd(&Sedge[nt*16 + l15], p);
  }
  __syncthreads();
  // ---- loss + per-block graph reduction (block spans <=2 graphs) ----
  int gbase = n2g[ei[base]];
  if (tid < 64){
    int e = base + tid;
    float sv = Sedge[tid] + ob3[0] + dnoise[e];
    float l = 0.5f*sv*sv;
    int g = n2g[ei[e]] - gbase;     // in {0,1}
    atomicAdd(&part[g & 3], l);
  }
  __syncthreads();
  if (tid < 2 && (gbase + tid) < G)
    atomicAdd(&out[gbase + tid], part[tid]);
}

// =========================== host ===========================
static inline size_t alignup(size_t v){ return (v + 255) & ~(size_t)255; }

extern "C" void kernel_launch(void* const* d_in, const int* in_sizes, int n_in,
                              void* d_out, int out_size, void* d_ws, size_t ws_size,
                              hipStream_t stream) {
  const int*   at    = (const int*)  d_in[0];
  const int*   ei    = (const int*)  d_in[1];
  const int*   etype = (const int*)  d_in[2];
  const int*   n2g   = (const int*)  d_in[3];
  const int*   nl    = (const int*)  d_in[4];
  const float* pos   = (const float*)d_in[5];
  const float* dnoi  = (const float*)d_in[6];
  const float* sig   = (const float*)d_in[7];
  const float* nemb  = (const float*)d_in[8];
  const float* eemb  = (const float*)d_in[9];
  const float* inW1  = (const float*)d_in[10];
  const float* inb1  = (const float*)d_in[11];
  const float* inW2  = (const float*)d_in[12];
  const float* inb2  = (const float*)d_in[13];
  const float* gW1   = (const float*)d_in[14];
  const float* gb1   = (const float*)d_in[15];
  const float* gW2   = (const float*)d_in[16];
  const float* gb2   = (const float*)d_in[17];
  const float* oW1   = (const float*)d_in[18];
  const float* ob1   = (const float*)d_in[19];
  const float* oW2   = (const float*)d_in[20];
  const float* ob2   = (const float*)d_in[21];
  const float* oW3   = (const float*)d_in[22];
  const float* ob3   = (const float*)d_in[23];
  float* out = (float*)d_out;

  const int N = in_sizes[0];
  const int E = in_sizes[2];
  const int G = in_sizes[4];
  const int H = 256;

  char* w = (char*)d_ws;
  size_t off = 0;
  size_t o_attr  = off; off = alignup(off + (size_t)E*H*2);
  size_t o_xF    = off; off = alignup(off + (size_t)N*H*2);
  size_t o_pd    = off; off = alignup(off + (size_t)E*4);
  size_t o_cnt   = off; off = alignup(off + (size_t)N*4);
  size_t o_inl   = off; off = alignup(off + (size_t)N*8*4);
  size_t o_w2t   = off; off = alignup(off + (size_t)H*H*2);
  size_t o_gw1t  = off; off = alignup(off + (size_t)4*H*H*2);
  size_t o_gw2t  = off; off = alignup(off + (size_t)4*H*H*2);
  size_t o_ow1t  = off; off = alignup(off + (size_t)H*2*H*2);
  size_t o_ow2t  = off; off = alignup(off + (size_t)(H/2)*H*2);
  (void)ws_size; (void)n_in; (void)out_size;

  short* attrS = (short*)(w + o_attr);
  short* xF    = (short*)(w + o_xF);
  float* pd    = (float*)(w + o_pd);
  int*   cnt   = (int*)  (w + o_cnt);
  int*   inl   = (int*)  (w + o_inl);
  short* w2t   = (short*)(w + o_w2t);
  short* gw1t  = (short*)(w + o_gw1t);
  short* gw2t  = (short*)(w + o_gw2t);
  short* ow1t  = (short*)(w + o_ow1t);
  short* ow2t  = (short*)(w + o_ow2t);

  hipMemsetAsync(cnt, 0, (size_t)N*4, stream);
  hipMemsetAsync(out, 0, (size_t)G*4, stream);

  k_cvtAll<<<368, 256, 0, stream>>>(inW2, gW1, gW2, oW1, oW2,
                                    w2t, gw1t, gw2t, ow1t, ow2t);

  k_pre<<<(E+255)/256, 256, 0, stream>>>(ei, n2g, nl, sig, pos, dnoi, E, pd, cnt, inl);
  k_attr<<<E/64, 256, 0, stream>>>(pd, inW1, inb1, w2t, inb2, etype, eemb, attrS, E);

  k_conv4<<<G, 256, 0, stream>>>(at, nemb, attrS, ei, cnt, inl,
                                 gw1t, gb1, gw2t, gb2, xF);

  k_head<<<E/64, 256, 0, stream>>>(xF, attrS, ei, ow1t, ob1, ow2t, ob2,
                                   oW3, ob3, dnoi, n2g, out, E, G);
}

// Round 14
// 540.918 us; speedup vs baseline: 1.0983x; 1.0983x over previous
//
#include <hip/hip_runtime.h>
#include <math.h>

typedef unsigned int u32;
typedef __attribute__((ext_vector_type(8))) short bf16x8;
typedef __attribute__((ext_vector_type(4))) float f32x4;

#define MFMA16(a,b,c) __builtin_amdgcn_mfma_f32_16x16x32_bf16(a,b,c,0,0,0)

// ---------- bf16 helpers ----------
__device__ inline u32 bf16r(float x){
  u32 u = __float_as_uint(x);
  return (u + 0x7fffu + ((u >> 16) & 1u)) >> 16;
}
__device__ inline u32 pack2(float a, float b){ return bf16r(a) | (bf16r(b) << 16); }
__device__ inline uint4 pack8(const float* f){
  uint4 v; v.x = pack2(f[0],f[1]); v.y = pack2(f[2],f[3]);
  v.z = pack2(f[4],f[5]); v.w = pack2(f[6],f[7]); return v;
}
__device__ inline float bf2f(short s){ return __uint_as_float(((u32)(unsigned short)s) << 16); }

// async global->LDS, 16B/lane; dest = wave-uniform base + lane*16 (src per-lane OK)
__device__ __forceinline__ void gload_lds16(const void* g, void* l){
  __builtin_amdgcn_global_load_lds((const __attribute__((address_space(1))) unsigned int*)g,
                                   (__attribute__((address_space(3))) unsigned int*)l,
                                   16, 0, 0);
}

// LDS fragment offset (shorts) in paired-macro-row granule layout
__device__ __forceinline__ int frag_off(int f, int quad){
  return (f>>1)*64 + (f&1)*32 + ((quad ^ ((f>>1)&3))*8);
}

// xls float4-granule swizzle (bank-verified for 16-ch and 8-ch thread maps)
__device__ __forceinline__ int xg(int g, int r){ return g ^ ((r ^ (g>>3)) & 7); }

// ---------- merged weight converter: f32 [K][Nf] -> bf16 row-major [Nf][K] ----------
__global__ void k_cvtAll(const float* __restrict__ inW2, const float* __restrict__ gW1,
                         const float* __restrict__ gW2, const float* __restrict__ oW1,
                         const float* __restrict__ oW2,
                         short* __restrict__ w2t, short* __restrict__ gw1t,
                         short* __restrict__ gw2t, short* __restrict__ ow1t,
                         short* __restrict__ ow2t){
  int gidx = blockIdx.x*256 + threadIdx.x;
  const float* src; short* dst; int t, K8, Nf;
  if (gidx < 8192)      { src = inW2; dst = w2t; t = gidx; K8 = 32; Nf = 256; }
  else if (gidx < 40960){ int r = gidx-8192;  int c = r>>13; t = r&8191;
                          src = gW1 + (size_t)c*65536; dst = gw1t + (size_t)c*65536; K8 = 32; Nf = 256; }
  else if (gidx < 73728){ int r = gidx-40960; int c = r>>13; t = r&8191;
                          src = gW2 + (size_t)c*65536; dst = gw2t + (size_t)c*65536; K8 = 32; Nf = 256; }
  else if (gidx < 90112){ t = gidx-73728; src = oW1; dst = ow1t; K8 = 64; Nf = 256; }
  else if (gidx < 94208){ t = gidx-90112; src = oW2; dst = ow2t; K8 = 32; Nf = 128; }
  else return;
  int f = t / K8, c = t - f*K8;
  float v[8];
  #pragma unroll
  for (int j=0;j<8;j++) v[j] = src[(size_t)(c*8+j)*Nf + f];
  ((uint4*)dst)[t] = pack8(v);
}

// ---------- per-edge scalars + CSR in-edge lists ----------
__global__ void k_pre(const int* __restrict__ ei, const int* __restrict__ n2g,
                      const int* __restrict__ nl, const float* __restrict__ sigmas,
                      const float* __restrict__ pos, const float* __restrict__ dn, int E,
                      float* __restrict__ pd, int* __restrict__ cnt, int* __restrict__ inlist){
  int e = blockIdx.x*256 + threadIdx.x;
  if (e >= E) return;
  int r = ei[e], c = ei[E+e];
  float sg = sigmas[nl[n2g[r]]];
  float dx = pos[3*r]-pos[3*c], dy = pos[3*r+1]-pos[3*c+1], dz = pos[3*r+2]-pos[3*c+2];
  float d = sqrtf(dx*dx + dy*dy + dz*dz);
  pd[e] = d + dn[e]*sg;
  int slot = atomicAdd(&cnt[c], 1);
  if (slot < 8) inlist[c*8 + slot] = e;
}

// ---------- edge_attr: barrier-free, no LDS. B computed in registers ----------
__global__ __launch_bounds__(256) void k_attr(
    const float* __restrict__ pd, const float* __restrict__ W1, const float* __restrict__ b1,
    const short* __restrict__ W2t, const float* __restrict__ b2,
    const int* __restrict__ etype, const float* __restrict__ eemb,
    short* __restrict__ attr, int E)
{
  int tid = threadIdx.x;
  int base = blockIdx.x*64;
  int wv = tid>>6, lane = tid&63, quad = lane>>4, l15 = lane&15;
  float pdv[4];
  #pragma unroll
  for (int nt=0;nt<4;nt++) pdv[nt] = pd[base + nt*16 + l15];
  f32x4 acc[4][4];
  #pragma unroll
  for (int mt=0;mt<4;mt++) for (int nt=0;nt<4;nt++) acc[mt][nt] = (f32x4)0.f;
  #pragma unroll
  for (int s=0; s<8; s++){
    int k0 = s*32 + quad*8;
    float4 w1a = *(const float4*)(W1 + k0), w1b = *(const float4*)(W1 + k0 + 4);
    float4 b1a = *(const float4*)(b1 + k0), b1b = *(const float4*)(b1 + k0 + 4);
    bf16x8 a[4], b[4];
    #pragma unroll
    for (int mt=0;mt<4;mt++){
      int f = (wv*4+mt)*16 + l15;
      a[mt] = *(const bf16x8*)(W2t + (size_t)f*256 + k0);
    }
    #pragma unroll
    for (int nt=0;nt<4;nt++){
      float p = pdv[nt];
      float f[8] = {fmaxf(p*w1a.x+b1a.x,0.f), fmaxf(p*w1a.y+b1a.y,0.f),
                    fmaxf(p*w1a.z+b1a.z,0.f), fmaxf(p*w1a.w+b1a.w,0.f),
                    fmaxf(p*w1b.x+b1b.x,0.f), fmaxf(p*w1b.y+b1b.y,0.f),
                    fmaxf(p*w1b.z+b1b.z,0.f), fmaxf(p*w1b.w+b1b.w,0.f)};
      uint4 u = pack8(f);
      b[nt] = *(bf16x8*)&u;
    }
    #pragma unroll
    for (int mt=0;mt<4;mt++)
      #pragma unroll
      for (int nt=0;nt<4;nt++)
        acc[mt][nt] = MFMA16(a[mt], b[nt], acc[mt][nt]);
  }
  #pragma unroll
  for (int nt=0;nt<4;nt++){
    int e = base + nt*16 + l15;
    int et = etype[e];
    #pragma unroll
    for (int mt=0;mt<4;mt++){
      int f0 = (wv*4+mt)*16 + quad*4;
      float4 bb = *(const float4*)(b2 + f0);
      float4 em = *(const float4*)(eemb + (size_t)et*256 + f0);
      float v0 = (acc[mt][nt][0]+bb.x)*em.x, v1 = (acc[mt][nt][1]+bb.y)*em.y;
      float v2 = (acc[mt][nt][2]+bb.z)*em.z, v3 = (acc[mt][nt][3]+bb.w)*em.w;
      uint2 v; v.x = pack2(v0,v1); v.y = pack2(v2,v3);
      *(uint2*)(attr + (size_t)e*256 + f0) = v;
    }
  }
}

// ---------- per-graph fused 4-conv kernel, 512 threads (8 waves = 2/SIMD) ----------
// 1 block = 1 graph. attr staged once (92 KB); x in LDS fp32; zero global traffic in loop.
#define EPG 180
__global__ __launch_bounds__(512,1) void k_conv4(
    const int* __restrict__ at, const float* __restrict__ nemb,
    const short* __restrict__ attrS, const int* __restrict__ ei,
    const int* __restrict__ cnt, const int* __restrict__ inlist,
    const short* __restrict__ gw1t, const float* __restrict__ gb1,
    const short* __restrict__ gw2t, const float* __restrict__ gb2,
    short* __restrict__ xF)
{
  __shared__ float xls[32*256];       // 32 KB
  __shared__ uint4 AlsV[32*32];       // 16 KB; T1 aliases
  __shared__ uint4 attrLV[EPG*32];    // 92160 B: [edge][256 shorts], linear
  short* Als = (short*)AlsV;
  short* T1  = Als;
  short* attrL = (short*)attrLV;
  int tid = threadIdx.x;
  int nbase = blockIdx.x*32;
  int ebase = blockIdx.x*EPG;
  int wv = tid>>6, lane = tid&63, quad = lane>>4, l15 = lane&15;
  int jl = tid>>4, ch = tid&15;       // 16 threads/node, 16 feats each
  // ---- stage attr for this graph: 92160 B contiguous, 90 x 1024B wave-chunks ----
  {
    const char* src = (const char*)(attrS + (size_t)ebase*256) + lane*16;
    char* dst = (char*)attrLV;
    #pragma unroll
    for (int i=0; i<12; i++){
      int r = i*8 + wv;
      if (r < 90) gload_lds16(src + r*1024, dst + r*1024);
    }
  }
  // ---- hoist in-edge topology into registers (local edge ids) ----
  int deg, eid[8], rl[8];
  {
    int j = nbase + jl;
    deg = min(cnt[j], 8);
    #pragma unroll
    for (int s=0;s<8;s++){
      eid[s] = (s < deg) ? (inlist[j*8 + s] - ebase) : 0;
      rl[s]  = (s < deg) ? (ei[ebase + eid[s]] - nbase) : 0;
    }
  }
  // ---- init xls from node_emb[at] ----
  {
    int a = at[nbase + jl];
    const float4* src = (const float4*)nemb + (size_t)a*64 + ch*4;
    float* xrow = xls + jl*256;
    #pragma unroll
    for (int q=0;q<4;q++)
      *(float4*)(xrow + (xg(ch*4+q, jl)<<2)) = src[q];
  }
  __syncthreads();   // drains gloads (vmcnt) + ds writes
  for (int c=0; c<4; c++){
    const short* W1t = gw1t + (size_t)c*65536;
    const short* W2t = gw2t + (size_t)c*65536;
    const float* b1 = gb1 + c*256;
    const float* b2 = gb2 + c*256;
    // ---- gather staging into Als (bf16): hin[j] = x[j] + sum relu(x[r]+attr[e]) ----
    {
      float f[16];
      const float* xrow = xls + jl*256;
      #pragma unroll
      for (int q=0;q<4;q++){
        float4 v = *(const float4*)(xrow + (xg(ch*4+q, jl)<<2));
        f[q*4]=v.x; f[q*4+1]=v.y; f[q*4+2]=v.z; f[q*4+3]=v.w;
      }
      for (int sIt=0; sIt<deg; sIt++){
        int r = rl[sIt];
        const float* xr = xls + r*256;
        const short* ar = attrL + eid[sIt]*256 + ch*16;
        #pragma unroll
        for (int q=0;q<4;q++){
          float4 xv = *(const float4*)(xr + (xg(ch*4+q, r)<<2));
          uint2 a2 = *(const uint2*)(ar + q*4);
          f[q*4]   += fmaxf(xv.x + __uint_as_float(a2.x<<16), 0.f);
          f[q*4+1] += fmaxf(xv.y + __uint_as_float(a2.x&0xffff0000u), 0.f);
          f[q*4+2] += fmaxf(xv.z + __uint_as_float(a2.y<<16), 0.f);
          f[q*4+3] += fmaxf(xv.w + __uint_as_float(a2.y&0xffff0000u), 0.f);
        }
      }
      #pragma unroll
      for (int qq=0;qq<2;qq++){
        int cc = ch*2 + qq;
        *(uint4*)(Als + jl*256 + ((cc ^ (jl&7))*8)) = pack8(f + qq*8);
      }
    }
    __syncthreads();
    // ---- GEMM1: M=256 (8 waves x 32 feats), N=32, K=256; A direct from L2 ----
    f32x4 acc[2][2];
    #pragma unroll
    for (int mt=0;mt<2;mt++) for (int nt=0;nt<2;nt++) acc[mt][nt] = (f32x4)0.f;
    #pragma unroll
    for (int s=0; s<8; s++){
      bf16x8 a[2], b[2];
      #pragma unroll
      for (int mt=0;mt<2;mt++)
        a[mt] = *(const bf16x8*)(W1t + (size_t)((wv*2+mt)*16 + l15)*256 + s*32 + quad*8);
      #pragma unroll
      for (int nt=0;nt<2;nt++){
        int n = nt*16 + l15; int cc = s*4 + quad;
        b[nt] = *(const bf16x8*)(Als + n*256 + ((cc ^ (n&7))*8));
      }
      #pragma unroll
      for (int mt=0;mt<2;mt++)
        #pragma unroll
        for (int nt=0;nt<2;nt++)
          acc[mt][nt] = MFMA16(a[mt], b[nt], acc[mt][nt]);
    }
    __syncthreads();   // all waves done reading Als; T1 aliases it
    #pragma unroll
    for (int mt=0;mt<2;mt++){
      int f0 = (wv*2+mt)*16 + quad*4;
      float4 bb = *(const float4*)(b1 + f0);
      int cg = f0 >> 3, off = (quad&1)*4;
      #pragma unroll
      for (int nt=0;nt<2;nt++){
        int n = nt*16 + l15;
        float v0 = fmaxf(acc[mt][nt][0]+bb.x,0.f), v1 = fmaxf(acc[mt][nt][1]+bb.y,0.f);
        float v2 = fmaxf(acc[mt][nt][2]+bb.z,0.f), v3 = fmaxf(acc[mt][nt][3]+bb.w,0.f);
        uint2 v; v.x = pack2(v0,v1); v.y = pack2(v2,v3);
        *(uint2*)(T1 + n*256 + ((cg ^ (n&7))*8) + off) = v;
      }
    }
    __syncthreads();
    // ---- GEMM2 ----
    f32x4 acc2[2][2];
    #pragma unroll
    for (int mt=0;mt<2;mt++) for (int nt=0;nt<2;nt++) acc2[mt][nt] = (f32x4)0.f;
    #pragma unroll
    for (int s=0; s<8; s++){
      bf16x8 a[2], b[2];
      #pragma unroll
      for (int mt=0;mt<2;mt++)
        a[mt] = *(const bf16x8*)(W2t + (size_t)((wv*2+mt)*16 + l15)*256 + s*32 + quad*8);
      #pragma unroll
      for (int nt=0;nt<2;nt++){
        int n = nt*16 + l15; int cc = s*4 + quad;
        b[nt] = *(const bf16x8*)(T1 + n*256 + ((cc ^ (n&7))*8));
      }
      #pragma unroll
      for (int mt=0;mt<2;mt++)
        #pragma unroll
        for (int nt=0;nt<2;nt++)
          acc2[mt][nt] = MFMA16(a[mt], b[nt], acc2[mt][nt]);
    }
    // ---- residual update into xls (relu for c<3) ----
    #pragma unroll
    for (int mt=0;mt<2;mt++){
      int f0 = (wv*2+mt)*16 + quad*4;
      float4 bb = *(const float4*)(b2 + f0);
      int g = f0 >> 2;
      #pragma unroll
      for (int nt=0;nt<2;nt++){
        int n = nt*16 + l15;
        float* px = xls + n*256 + (xg(g, n)<<2);
        float4 xv = *(float4*)px;
        float h0 = acc2[mt][nt][0]+bb.x, h1 = acc2[mt][nt][1]+bb.y;
        float h2 = acc2[mt][nt][2]+bb.z, h3 = acc2[mt][nt][3]+bb.w;
        if (c < 3){ h0=fmaxf(h0,0.f); h1=fmaxf(h1,0.f); h2=fmaxf(h2,0.f); h3=fmaxf(h3,0.f); }
        xv.x += h0; xv.y += h1; xv.z += h2; xv.w += h3;
        *(float4*)px = xv;
      }
    }
    __syncthreads();   // xls updates visible before next gather / writeout
  }
  // ---- writeout xF (bf16, row-major) ----
  {
    const float* xrow = xls + jl*256;
    float f[16];
    #pragma unroll
    for (int q=0;q<4;q++){
      float4 v = *(const float4*)(xrow + (xg(ch*4+q, jl)<<2));
      f[q*4]=v.x; f[q*4+1]=v.y; f[q*4+2]=v.z; f[q*4+3]=v.w;
    }
    #pragma unroll
    for (int qq=0;qq<2;qq++)
      *(uint4*)(xF + (size_t)(nbase+jl)*256 + ch*16 + qq*8) = pack8(f + qq*8);
  }
}

// ---------- fully fused head: L1 GEMM -> T(LDS) -> L2 GEMM -> L3 dot -> loss reduce ----------
// 64 edges/block; x is bf16; 2 global atomics/block
__global__ __launch_bounds__(256,2) void k_head(
    const short* __restrict__ xF, const short* __restrict__ attrS,
    const int* __restrict__ ei,
    const short* __restrict__ W1t, const float* __restrict__ ob1,
    const short* __restrict__ W2t, const float* __restrict__ ob2,
    const float* __restrict__ W3, const float* __restrict__ ob3,
    const float* __restrict__ dnoise, const int* __restrict__ n2g,
    float* __restrict__ out, int E, int G)
{
  __shared__ uint4 BlsV[16*256];   // 64 KB; T (32 KB) aliases after L1
  __shared__ float Sedge[64];
  __shared__ float part[4];
  short* Bls = (short*)BlsV;
  short* T   = (short*)BlsV;
  int tid = threadIdx.x;
  int base = blockIdx.x*64;
  int wv = tid>>6, lane = tid&63, quad = lane>>4, l15 = lane&15;
  if (tid < 64) Sedge[tid] = 0.f;
  if (tid < 4) part[tid] = 0.f;
  // attr slices (s=8..15): per-lane-source gload
  {
    int g = wv*64 + lane;
    int p = g>>3, hi = (g>>2)&1, cs = g&3;
    int n = p*2 + hi, cc = cs ^ (p&3);
    const short* srcb = attrS + (size_t)(base+n)*256 + cc*8;
    #pragma unroll
    for (int s=8; s<16; s++)
      gload_lds16(srcb + (s-8)*32, (char*)Bls + (size_t)s*4096 + wv*1024);
  }
  // xr*xc slices (s=0..7), bf16 inputs
  {
    int g = tid;
    int p = g>>3, hi = (g>>2)&1, cs = g&3;
    int n = p*2 + hi, cc = cs ^ (p&3);
    int rr = ei[base+n], rc = ei[E+base+n];
    const short* xr = xF + (size_t)rr*256 + cc*8;
    const short* xc = xF + (size_t)rc*256 + cc*8;
    #pragma unroll
    for (int s=0; s<8; s++){
      bf16x8 va = *(const bf16x8*)(xr + s*32);
      bf16x8 vb = *(const bf16x8*)(xc + s*32);
      float f[8];
      #pragma unroll
      for (int j=0;j<8;j++) f[j] = bf2f(va[j])*bf2f(vb[j]);
      *(uint4*)(Bls + (size_t)s*2048 + g*8) = pack8(f);
    }
  }
  __syncthreads();
  // ---- L1: 16 barrier-free K-slices; M=256, N=64 ----
  f32x4 acc[4][4];
  #pragma unroll
  for (int mt=0;mt<4;mt++) for (int nt=0;nt<4;nt++) acc[mt][nt] = (f32x4)0.f;
  #pragma unroll
  for (int s=0; s<16; s++){
    bf16x8 a[4], b[4];
    #pragma unroll
    for (int mt=0;mt<4;mt++)
      a[mt] = *(const bf16x8*)(W1t + (size_t)((wv*4+mt)*16 + l15)*512 + s*32 + quad*8);
    #pragma unroll
    for (int nt=0;nt<4;nt++)
      b[nt] = *(const bf16x8*)(Bls + (size_t)s*2048 + frag_off(nt*16 + l15, quad));
    #pragma unroll
    for (int mt=0;mt<4;mt++)
      #pragma unroll
      for (int nt=0;nt<4;nt++)
        acc[mt][nt] = MFMA16(a[mt], b[nt], acc[mt][nt]);
  }
  __syncthreads();   // all waves done reading Bls; T aliases it
  #pragma unroll
  for (int mt=0;mt<4;mt++){
    int f0 = (wv*4+mt)*16 + quad*4;
    float4 bb = *(const float4*)(ob1 + f0);
    int c = f0 >> 3, off = (quad&1)*4;
    #pragma unroll
    for (int nt=0;nt<4;nt++){
      int n = nt*16 + l15;
      float v0 = fmaxf(acc[mt][nt][0]+bb.x,0.f), v1 = fmaxf(acc[mt][nt][1]+bb.y,0.f);
      float v2 = fmaxf(acc[mt][nt][2]+bb.z,0.f), v3 = fmaxf(acc[mt][nt][3]+bb.w,0.f);
      uint2 v; v.x = pack2(v0,v1); v.y = pack2(v2,v3);
      *(uint2*)(T + n*256 + ((c ^ (n&7))*8) + off) = v;
    }
  }
  __syncthreads();
  // ---- L2: 8 barrier-free K-slices; M=128, N=64; A direct (L2-hot) ----
  f32x4 acc2[2][4];
  #pragma unroll
  for (int mt=0;mt<2;mt++) for (int nt=0;nt<4;nt++) acc2[mt][nt] = (f32x4)0.f;
  #pragma unroll
  for (int s=0; s<8; s++){
    bf16x8 a[2], b[4];
    #pragma unroll
    for (int mt=0;mt<2;mt++)
      a[mt] = *(const bf16x8*)(W2t + (size_t)((wv*2+mt)*16 + l15)*256 + s*32 + quad*8);
    #pragma unroll
    for (int nt=0;nt<4;nt++){
      int n = nt*16 + l15; int cc = s*4 + quad;
      b[nt] = *(const bf16x8*)(T + n*256 + ((cc ^ (n&7))*8));
    }
    #pragma unroll
    for (int mt=0;mt<2;mt++)
      #pragma unroll
      for (int nt=0;nt<4;nt++)
        acc2[mt][nt] = MFMA16(a[mt], b[nt], acc2[mt][nt]);
  }
  // ---- L3 dot + cross-wave per-edge reduce ----
  float4 b2v[2], w3v[2];
  #pragma unroll
  for (int mt=0;mt<2;mt++){
    int f0 = (wv*2+mt)*16 + quad*4;
    b2v[mt] = *(const float4*)(ob2 + f0);
    w3v[mt] = *(const float4*)(W3 + f0);
  }
  #pragma unroll
  for (int nt=0;nt<4;nt++){
    float p = 0.f;
    #pragma unroll
    for (int mt=0;mt<2;mt++){
      p += fmaxf(acc2[mt][nt][0]+b2v[mt].x,0.f)*w3v[mt].x;
      p += fmaxf(acc2[mt][nt][1]+b2v[mt].y,0.f)*w3v[mt].y;
      p += fmaxf(acc2[mt][nt][2]+b2v[mt].z,0.f)*w3v[mt].z;
      p += fmaxf(acc2[mt][nt][3]+b2v[mt].w,0.f)*w3v[mt].w;
    }
    p += __shfl_xor(p, 16);
    p += __shfl_xor(p, 32);
    if (lane < 16) atomicAdd(&Sedge[nt*16 + l15], p);
  }
  __syncthreads();
  // ---- loss + per-block graph reduction (block spans <=2 graphs) ----
  int gbase = n2g[ei[base]];
  if (tid < 64){
    int e = base + tid;
    float sv = Sedge[tid] + ob3[0] + dnoise[e];
    float l = 0.5f*sv*sv;
    int g = n2g[ei[e]] - gbase;     // in {0,1}
    atomicAdd(&part[g & 3], l);
  }
  __syncthreads();
  if (tid < 2 && (gbase + tid) < G)
    atomicAdd(&out[gbase + tid], part[tid]);
}

// =========================== host ===========================
static inline size_t alignup(size_t v){ return (v + 255) & ~(size_t)255; }

extern "C" void kernel_launch(void* const* d_in, const int* in_sizes, int n_in,
                              void* d_out, int out_size, void* d_ws, size_t ws_size,
                              hipStream_t stream) {
  const int*   at    = (const int*)  d_in[0];
  const int*   ei    = (const int*)  d_in[1];
  const int*   etype = (const int*)  d_in[2];
  const int*   n2g   = (const int*)  d_in[3];
  const int*   nl    = (const int*)  d_in[4];
  const float* pos   = (const float*)d_in[5];
  const float* dnoi  = (const float*)d_in[6];
  const float* sig   = (const float*)d_in[7];
  const float* nemb  = (const float*)d_in[8];
  const float* eemb  = (const float*)d_in[9];
  const float* inW1  = (const float*)d_in[10];
  const float* inb1  = (const float*)d_in[11];
  const float* inW2  = (const float*)d_in[12];
  const float* inb2  = (const float*)d_in[13];
  const float* gW1   = (const float*)d_in[14];
  const float* gb1   = (const float*)d_in[15];
  const float* gW2   = (const float*)d_in[16];
  const float* gb2   = (const float*)d_in[17];
  const float* oW1   = (const float*)d_in[18];
  const float* ob1   = (const float*)d_in[19];
  const float* oW2   = (const float*)d_in[20];
  const float* ob2   = (const float*)d_in[21];
  const float* oW3   = (const float*)d_in[22];
  const float* ob3   = (const float*)d_in[23];
  float* out = (float*)d_out;

  const int N = in_sizes[0];
  const int E = in_sizes[2];
  const int G = in_sizes[4];
  const int H = 256;

  char* w = (char*)d_ws;
  size_t off = 0;
  size_t o_attr  = off; off = alignup(off + (size_t)E*H*2);
  size_t o_xF    = off; off = alignup(off + (size_t)N*H*2);
  size_t o_pd    = off; off = alignup(off + (size_t)E*4);
  size_t o_cnt   = off; off = alignup(off + (size_t)N*4);
  size_t o_inl   = off; off = alignup(off + (size_t)N*8*4);
  size_t o_w2t   = off; off = alignup(off + (size_t)H*H*2);
  size_t o_gw1t  = off; off = alignup(off + (size_t)4*H*H*2);
  size_t o_gw2t  = off; off = alignup(off + (size_t)4*H*H*2);
  size_t o_ow1t  = off; off = alignup(off + (size_t)H*2*H*2);
  size_t o_ow2t  = off; off = alignup(off + (size_t)(H/2)*H*2);
  (void)ws_size; (void)n_in; (void)out_size;

  short* attrS = (short*)(w + o_attr);
  short* xF    = (short*)(w + o_xF);
  float* pd    = (float*)(w + o_pd);
  int*   cnt   = (int*)  (w + o_cnt);
  int*   inl   = (int*)  (w + o_inl);
  short* w2t   = (short*)(w + o_w2t);
  short* gw1t  = (short*)(w + o_gw1t);
  short* gw2t  = (short*)(w + o_gw2t);
  short* ow1t  = (short*)(w + o_ow1t);
  short* ow2t  = (short*)(w + o_ow2t);

  hipMemsetAsync(cnt, 0, (size_t)N*4, stream);
  hipMemsetAsync(out, 0, (size_t)G*4, stream);

  k_cvtAll<<<368, 256, 0, stream>>>(inW2, gW1, gW2, oW1, oW2,
                                    w2t, gw1t, gw2t, ow1t, ow2t);

  k_pre<<<(E+255)/256, 256, 0, stream>>>(ei, n2g, nl, sig, pos, dnoi, E, pd, cnt, inl);
  k_attr<<<E/64, 256, 0, stream>>>(pd, inW1, inb1, w2t, inb2, etype, eemb, attrS, E);

  k_conv4<<<G, 512, 0, stream>>>(at, nemb, attrS, ei, cnt, inl,
                                 gw1t, gb1, gw2t, gb2, xF);

  k_head<<<E/64, 256, 0, stream>>>(xF, attrS, ei, ow1t, ob1, ow2t, ob2,
                                   oW3, ob3, dnoi, n2g, out, E, G);
}

// Round 15
// 535.048 us; speedup vs baseline: 1.1104x; 1.0110x over previous
//
#include <hip/hip_runtime.h>
#include <math.h>

typedef unsigned int u32;
typedef __attribute__((ext_vector_type(8))) short bf16x8;
typedef __attribute__((ext_vector_type(4))) float f32x4;

#define MFMA16(a,b,c) __builtin_amdgcn_mfma_f32_16x16x32_bf16(a,b,c,0,0,0)

// ---------- bf16 helpers ----------
__device__ inline u32 bf16r(float x){
  u32 u = __float_as_uint(x);
  return (u + 0x7fffu + ((u >> 16) & 1u)) >> 16;
}
__device__ inline u32 pack2(float a, float b){ return bf16r(a) | (bf16r(b) << 16); }
__device__ inline uint4 pack8(const float* f){
  uint4 v; v.x = pack2(f[0],f[1]); v.y = pack2(f[2],f[3]);
  v.z = pack2(f[4],f[5]); v.w = pack2(f[6],f[7]); return v;
}
__device__ inline float bf2f(short s){ return __uint_as_float(((u32)(unsigned short)s) << 16); }

// async global->LDS, 16B/lane; dest = wave-uniform base + lane*16 (src per-lane OK)
__device__ __forceinline__ void gload_lds16(const void* g, void* l){
  __builtin_amdgcn_global_load_lds((const __attribute__((address_space(1))) unsigned int*)g,
                                   (__attribute__((address_space(3))) unsigned int*)l,
                                   16, 0, 0);
}

// LDS fragment offset (shorts) in paired-macro-row granule layout
__device__ __forceinline__ int frag_off(int f, int quad){
  return (f>>1)*64 + (f&1)*32 + ((quad ^ ((f>>1)&3))*8);
}

// xls float4-granule swizzle (bank-verified for 32/16/8-ch thread maps)
__device__ __forceinline__ int xg(int g, int r){ return g ^ ((r ^ (g>>3)) & 7); }

// ---------- merged weight converter: f32 [K][Nf] -> bf16 row-major [Nf][K] ----------
__global__ void k_cvtAll(const float* __restrict__ inW2, const float* __restrict__ gW1,
                         const float* __restrict__ gW2, const float* __restrict__ oW1,
                         const float* __restrict__ oW2,
                         short* __restrict__ w2t, short* __restrict__ gw1t,
                         short* __restrict__ gw2t, short* __restrict__ ow1t,
                         short* __restrict__ ow2t){
  int gidx = blockIdx.x*256 + threadIdx.x;
  const float* src; short* dst; int t, K8, Nf;
  if (gidx < 8192)      { src = inW2; dst = w2t; t = gidx; K8 = 32; Nf = 256; }
  else if (gidx < 40960){ int r = gidx-8192;  int c = r>>13; t = r&8191;
                          src = gW1 + (size_t)c*65536; dst = gw1t + (size_t)c*65536; K8 = 32; Nf = 256; }
  else if (gidx < 73728){ int r = gidx-40960; int c = r>>13; t = r&8191;
                          src = gW2 + (size_t)c*65536; dst = gw2t + (size_t)c*65536; K8 = 32; Nf = 256; }
  else if (gidx < 90112){ t = gidx-73728; src = oW1; dst = ow1t; K8 = 64; Nf = 256; }
  else if (gidx < 94208){ t = gidx-90112; src = oW2; dst = ow2t; K8 = 32; Nf = 128; }
  else return;
  int f = t / K8, c = t - f*K8;
  float v[8];
  #pragma unroll
  for (int j=0;j<8;j++) v[j] = src[(size_t)(c*8+j)*Nf + f];
  ((uint4*)dst)[t] = pack8(v);
}

// ---------- per-edge scalars + CSR in-edge lists ----------
__global__ void k_pre(const int* __restrict__ ei, const int* __restrict__ n2g,
                      const int* __restrict__ nl, const float* __restrict__ sigmas,
                      const float* __restrict__ pos, const float* __restrict__ dn, int E,
                      float* __restrict__ pd, int* __restrict__ cnt, int* __restrict__ inlist){
  int e = blockIdx.x*256 + threadIdx.x;
  if (e >= E) return;
  int r = ei[e], c = ei[E+e];
  float sg = sigmas[nl[n2g[r]]];
  float dx = pos[3*r]-pos[3*c], dy = pos[3*r+1]-pos[3*c+1], dz = pos[3*r+2]-pos[3*c+2];
  float d = sqrtf(dx*dx + dy*dy + dz*dz);
  pd[e] = d + dn[e]*sg;
  int slot = atomicAdd(&cnt[c], 1);
  if (slot < 8) inlist[c*8 + slot] = e;
}

// ---------- edge_attr: barrier-free, no LDS. B computed in registers ----------
__global__ __launch_bounds__(256) void k_attr(
    const float* __restrict__ pd, const float* __restrict__ W1, const float* __restrict__ b1,
    const short* __restrict__ W2t, const float* __restrict__ b2,
    const int* __restrict__ etype, const float* __restrict__ eemb,
    short* __restrict__ attr, int E)
{
  int tid = threadIdx.x;
  int base = blockIdx.x*64;
  int wv = tid>>6, lane = tid&63, quad = lane>>4, l15 = lane&15;
  float pdv[4];
  #pragma unroll
  for (int nt=0;nt<4;nt++) pdv[nt] = pd[base + nt*16 + l15];
  f32x4 acc[4][4];
  #pragma unroll
  for (int mt=0;mt<4;mt++) for (int nt=0;nt<4;nt++) acc[mt][nt] = (f32x4)0.f;
  #pragma unroll
  for (int s=0; s<8; s++){
    int k0 = s*32 + quad*8;
    float4 w1a = *(const float4*)(W1 + k0), w1b = *(const float4*)(W1 + k0 + 4);
    float4 b1a = *(const float4*)(b1 + k0), b1b = *(const float4*)(b1 + k0 + 4);
    bf16x8 a[4], b[4];
    #pragma unroll
    for (int mt=0;mt<4;mt++){
      int f = (wv*4+mt)*16 + l15;
      a[mt] = *(const bf16x8*)(W2t + (size_t)f*256 + k0);
    }
    #pragma unroll
    for (int nt=0;nt<4;nt++){
      float p = pdv[nt];
      float f[8] = {fmaxf(p*w1a.x+b1a.x,0.f), fmaxf(p*w1a.y+b1a.y,0.f),
                    fmaxf(p*w1a.z+b1a.z,0.f), fmaxf(p*w1a.w+b1a.w,0.f),
                    fmaxf(p*w1b.x+b1b.x,0.f), fmaxf(p*w1b.y+b1b.y,0.f),
                    fmaxf(p*w1b.z+b1b.z,0.f), fmaxf(p*w1b.w+b1b.w,0.f)};
      uint4 u = pack8(f);
      b[nt] = *(bf16x8*)&u;
    }
    #pragma unroll
    for (int mt=0;mt<4;mt++)
      #pragma unroll
      for (int nt=0;nt<4;nt++)
        acc[mt][nt] = MFMA16(a[mt], b[nt], acc[mt][nt]);
  }
  #pragma unroll
  for (int nt=0;nt<4;nt++){
    int e = base + nt*16 + l15;
    int et = etype[e];
    #pragma unroll
    for (int mt=0;mt<4;mt++){
      int f0 = (wv*4+mt)*16 + quad*4;
      float4 bb = *(const float4*)(b2 + f0);
      float4 em = *(const float4*)(eemb + (size_t)et*256 + f0);
      float v0 = (acc[mt][nt][0]+bb.x)*em.x, v1 = (acc[mt][nt][1]+bb.y)*em.y;
      float v2 = (acc[mt][nt][2]+bb.z)*em.z, v3 = (acc[mt][nt][3]+bb.w)*em.w;
      uint2 v; v.x = pack2(v0,v1); v.y = pack2(v2,v3);
      *(uint2*)(attr + (size_t)e*256 + f0) = v;
    }
  }
}

// ---------- per-graph fused 4-conv kernel, 1024 threads (16 waves = 4/SIMD) ----------
// 1 block = 1 graph. attr staged once (92 KB); x in LDS fp32; T1 separate (3 barriers/conv).
#define EPG 180
__global__ __launch_bounds__(1024,1) void k_conv4(
    const int* __restrict__ at, const float* __restrict__ nemb,
    const short* __restrict__ attrS, const int* __restrict__ ei,
    const int* __restrict__ cnt, const int* __restrict__ inlist,
    const short* __restrict__ gw1t, const float* __restrict__ gb1,
    const short* __restrict__ gw2t, const float* __restrict__ gb2,
    short* __restrict__ xF)
{
  __shared__ float xls[32*256];       // 32 KB
  __shared__ uint4 AlsV[32*32];       // 16 KB
  __shared__ uint4 T1V [32*32];       // 16 KB (separate: no barrier between GEMM1 and T1 write)
  __shared__ uint4 attrLV[EPG*32];    // 92160 B: [edge][256 shorts], linear
  short* Als = (short*)AlsV;
  short* T1  = (short*)T1V;
  short* attrL = (short*)attrLV;
  int tid = threadIdx.x;
  int nbase = blockIdx.x*32;
  int ebase = blockIdx.x*EPG;
  int wv = tid>>6, lane = tid&63, quad = lane>>4, l15 = lane&15;
  int jl = tid>>5, ch = tid&31;       // 32 threads/node, 8 feats each
  // ---- stage attr for this graph: 92160 B contiguous, 90 x 1024B wave-chunks ----
  {
    const char* src = (const char*)(attrS + (size_t)ebase*256) + lane*16;
    char* dst = (char*)attrLV;
    #pragma unroll
    for (int i=0; i<6; i++){
      int r = i*16 + wv;
      if (r < 90) gload_lds16(src + r*1024, dst + r*1024);
    }
  }
  // ---- hoist in-edge topology into registers (local edge ids) ----
  int deg, eid[8], rl[8];
  {
    int j = nbase + jl;
    deg = min(cnt[j], 8);
    #pragma unroll
    for (int s=0;s<8;s++){
      eid[s] = (s < deg) ? (inlist[j*8 + s] - ebase) : 0;
      rl[s]  = (s < deg) ? (ei[ebase + eid[s]] - nbase) : 0;
    }
  }
  // ---- init xls from node_emb[at] ----
  {
    int a = at[nbase + jl];
    const float4* src = (const float4*)nemb + (size_t)a*64 + ch*2;
    float* xrow = xls + jl*256;
    #pragma unroll
    for (int q=0;q<2;q++)
      *(float4*)(xrow + (xg(ch*2+q, jl)<<2)) = src[q];
  }
  __syncthreads();   // drains gloads (vmcnt) + ds writes
  for (int c=0; c<4; c++){
    const short* W1t = gw1t + (size_t)c*65536;
    const short* W2t = gw2t + (size_t)c*65536;
    const float* b1 = gb1 + c*256;
    const float* b2 = gb2 + c*256;
    // ---- gather staging into Als (bf16): hin[j] = x[j] + sum relu(x[r]+attr[e]) ----
    {
      float f[8];
      const float* xrow = xls + jl*256;
      #pragma unroll
      for (int q=0;q<2;q++){
        float4 v = *(const float4*)(xrow + (xg(ch*2+q, jl)<<2));
        f[q*4]=v.x; f[q*4+1]=v.y; f[q*4+2]=v.z; f[q*4+3]=v.w;
      }
      for (int sIt=0; sIt<deg; sIt++){
        int r = rl[sIt];
        const float* xr = xls + r*256;
        uint4 a4 = *(const uint4*)(attrL + eid[sIt]*256 + ch*8);
        #pragma unroll
        for (int q=0;q<2;q++){
          float4 xv = *(const float4*)(xr + (xg(ch*2+q, r)<<2));
          u32 lo = (q==0) ? a4.x : a4.z;
          u32 hi = (q==0) ? a4.y : a4.w;
          f[q*4]   += fmaxf(xv.x + __uint_as_float(lo<<16), 0.f);
          f[q*4+1] += fmaxf(xv.y + __uint_as_float(lo&0xffff0000u), 0.f);
          f[q*4+2] += fmaxf(xv.z + __uint_as_float(hi<<16), 0.f);
          f[q*4+3] += fmaxf(xv.w + __uint_as_float(hi&0xffff0000u), 0.f);
        }
      }
      *(uint4*)(Als + jl*256 + ((ch ^ (jl&7))*8)) = pack8(f);
    }
    __syncthreads();
    // ---- GEMM1: M=256 (16 waves x 16 feats), N=32, K=256; A direct from L2 ----
    f32x4 acc[2];
    acc[0] = (f32x4)0.f; acc[1] = (f32x4)0.f;
    #pragma unroll
    for (int s=0; s<8; s++){
      bf16x8 a = *(const bf16x8*)(W1t + (size_t)(wv*16 + l15)*256 + s*32 + quad*8);
      #pragma unroll
      for (int nt=0;nt<2;nt++){
        int n = nt*16 + l15; int cc = s*4 + quad;
        bf16x8 b = *(const bf16x8*)(Als + n*256 + ((cc ^ (n&7))*8));
        acc[nt] = MFMA16(a, b, acc[nt]);
      }
    }
    // T1 separate buffer: write immediately (depends only on registers)
    {
      int f0 = wv*16 + quad*4;
      float4 bb = *(const float4*)(b1 + f0);
      int cg = f0 >> 3, off = (quad&1)*4;
      #pragma unroll
      for (int nt=0;nt<2;nt++){
        int n = nt*16 + l15;
        float v0 = fmaxf(acc[nt][0]+bb.x,0.f), v1 = fmaxf(acc[nt][1]+bb.y,0.f);
        float v2 = fmaxf(acc[nt][2]+bb.z,0.f), v3 = fmaxf(acc[nt][3]+bb.w,0.f);
        uint2 v; v.x = pack2(v0,v1); v.y = pack2(v2,v3);
        *(uint2*)(T1 + n*256 + ((cg ^ (n&7))*8) + off) = v;
      }
    }
    __syncthreads();
    // ---- GEMM2 ----
    f32x4 acc2[2];
    acc2[0] = (f32x4)0.f; acc2[1] = (f32x4)0.f;
    #pragma unroll
    for (int s=0; s<8; s++){
      bf16x8 a = *(const bf16x8*)(W2t + (size_t)(wv*16 + l15)*256 + s*32 + quad*8);
      #pragma unroll
      for (int nt=0;nt<2;nt++){
        int n = nt*16 + l15; int cc = s*4 + quad;
        bf16x8 b = *(const bf16x8*)(T1 + n*256 + ((cc ^ (n&7))*8));
        acc2[nt] = MFMA16(a, b, acc2[nt]);
      }
    }
    // ---- residual update into xls (relu for c<3) ----
    {
      int f0 = wv*16 + quad*4;
      float4 bb = *(const float4*)(b2 + f0);
      int g = f0 >> 2;
      #pragma unroll
      for (int nt=0;nt<2;nt++){
        int n = nt*16 + l15;
        float* px = xls + n*256 + (xg(g, n)<<2);
        float4 xv = *(float4*)px;
        float h0 = acc2[nt][0]+bb.x, h1 = acc2[nt][1]+bb.y;
        float h2 = acc2[nt][2]+bb.z, h3 = acc2[nt][3]+bb.w;
        if (c < 3){ h0=fmaxf(h0,0.f); h1=fmaxf(h1,0.f); h2=fmaxf(h2,0.f); h3=fmaxf(h3,0.f); }
        xv.x += h0; xv.y += h1; xv.z += h2; xv.w += h3;
        *(float4*)px = xv;
      }
    }
    __syncthreads();   // xls updates visible before next gather / writeout
  }
  // ---- writeout xF (bf16, row-major) ----
  {
    const float* xrow = xls + jl*256;
    float f[8];
    #pragma unroll
    for (int q=0;q<2;q++){
      float4 v = *(const float4*)(xrow + (xg(ch*2+q, jl)<<2));
      f[q*4]=v.x; f[q*4+1]=v.y; f[q*4+2]=v.z; f[q*4+3]=v.w;
    }
    *(uint4*)(xF + (size_t)(nbase+jl)*256 + ch*8) = pack8(f);
  }
}

// ---------- fully fused head: L1 GEMM -> T(LDS) -> L2 GEMM -> L3 dot -> loss reduce ----------
// 64 edges/block; x is bf16; 2 global atomics/block
__global__ __launch_bounds__(256,2) void k_head(
    const short* __restrict__ xF, const short* __restrict__ attrS,
    const int* __restrict__ ei,
    const short* __restrict__ W1t, const float* __restrict__ ob1,
    const short* __restrict__ W2t, const float* __restrict__ ob2,
    const float* __restrict__ W3, const float* __restrict__ ob3,
    const float* __restrict__ dnoise, const int* __restrict__ n2g,
    float* __restrict__ out, int E, int G)
{
  __shared__ uint4 BlsV[16*256];   // 64 KB; T (32 KB) aliases after L1
  __shared__ float Sedge[64];
  __shared__ float part[4];
  short* Bls = (short*)BlsV;
  short* T   = (short*)BlsV;
  int tid = threadIdx.x;
  int base = blockIdx.x*64;
  int wv = tid>>6, lane = tid&63, quad = lane>>4, l15 = lane&15;
  if (tid < 64) Sedge[tid] = 0.f;
  if (tid < 4) part[tid] = 0.f;
  // attr slices (s=8..15): per-lane-source gload
  {
    int g = wv*64 + lane;
    int p = g>>3, hi = (g>>2)&1, cs = g&3;
    int n = p*2 + hi, cc = cs ^ (p&3);
    const short* srcb = attrS + (size_t)(base+n)*256 + cc*8;
    #pragma unroll
    for (int s=8; s<16; s++)
      gload_lds16(srcb + (s-8)*32, (char*)Bls + (size_t)s*4096 + wv*1024);
  }
  // xr*xc slices (s=0..7), bf16 inputs
  {
    int g = tid;
    int p = g>>3, hi = (g>>2)&1, cs = g&3;
    int n = p*2 + hi, cc = cs ^ (p&3);
    int rr = ei[base+n], rc = ei[E+base+n];
    const short* xr = xF + (size_t)rr*256 + cc*8;
    const short* xc = xF + (size_t)rc*256 + cc*8;
    #pragma unroll
    for (int s=0; s<8; s++){
      bf16x8 va = *(const bf16x8*)(xr + s*32);
      bf16x8 vb = *(const bf16x8*)(xc + s*32);
      float f[8];
      #pragma unroll
      for (int j=0;j<8;j++) f[j] = bf2f(va[j])*bf2f(vb[j]);
      *(uint4*)(Bls + (size_t)s*2048 + g*8) = pack8(f);
    }
  }
  __syncthreads();
  // ---- L1: 16 barrier-free K-slices; M=256, N=64 ----
  f32x4 acc[4][4];
  #pragma unroll
  for (int mt=0;mt<4;mt++) for (int nt=0;nt<4;nt++) acc[mt][nt] = (f32x4)0.f;
  #pragma unroll
  for (int s=0; s<16; s++){
    bf16x8 a[4], b[4];
    #pragma unroll
    for (int mt=0;mt<4;mt++)
      a[mt] = *(const bf16x8*)(W1t + (size_t)((wv*4+mt)*16 + l15)*512 + s*32 + quad*8);
    #pragma unroll
    for (int nt=0;nt<4;nt++)
      b[nt] = *(const bf16x8*)(Bls + (size_t)s*2048 + frag_off(nt*16 + l15, quad));
    #pragma unroll
    for (int mt=0;mt<4;mt++)
      #pragma unroll
      for (int nt=0;nt<4;nt++)
        acc[mt][nt] = MFMA16(a[mt], b[nt], acc[mt][nt]);
  }
  __syncthreads();   // all waves done reading Bls; T aliases it
  #pragma unroll
  for (int mt=0;mt<4;mt++){
    int f0 = (wv*4+mt)*16 + quad*4;
    float4 bb = *(const float4*)(ob1 + f0);
    int c = f0 >> 3, off = (quad&1)*4;
    #pragma unroll
    for (int nt=0;nt<4;nt++){
      int n = nt*16 + l15;
      float v0 = fmaxf(acc[mt][nt][0]+bb.x,0.f), v1 = fmaxf(acc[mt][nt][1]+bb.y,0.f);
      float v2 = fmaxf(acc[mt][nt][2]+bb.z,0.f), v3 = fmaxf(acc[mt][nt][3]+bb.w,0.f);
      uint2 v; v.x = pack2(v0,v1); v.y = pack2(v2,v3);
      *(uint2*)(T + n*256 + ((c ^ (n&7))*8) + off) = v;
    }
  }
  __syncthreads();
  // ---- L2: 8 barrier-free K-slices; M=128, N=64; A direct (L2-hot) ----
  f32x4 acc2[2][4];
  #pragma unroll
  for (int mt=0;mt<2;mt++) for (int nt=0;nt<4;nt++) acc2[mt][nt] = (f32x4)0.f;
  #pragma unroll
  for (int s=0; s<8; s++){
    bf16x8 a[2], b[4];
    #pragma unroll
    for (int mt=0;mt<2;mt++)
      a[mt] = *(const bf16x8*)(W2t + (size_t)((wv*2+mt)*16 + l15)*256 + s*32 + quad*8);
    #pragma unroll
    for (int nt=0;nt<4;nt++){
      int n = nt*16 + l15; int cc = s*4 + quad;
      b[nt] = *(const bf16x8*)(T + n*256 + ((cc ^ (n&7))*8));
    }
    #pragma unroll
    for (int mt=0;mt<2;mt++)
      #pragma unroll
      for (int nt=0;nt<4;nt++)
        acc2[mt][nt] = MFMA16(a[mt], b[nt], acc2[mt][nt]);
  }
  // ---- L3 dot + cross-wave per-edge reduce ----
  float4 b2v[2], w3v[2];
  #pragma unroll
  for (int mt=0;mt<2;mt++){
    int f0 = (wv*2+mt)*16 + quad*4;
    b2v[mt] = *(const float4*)(ob2 + f0);
    w3v[mt] = *(const float4*)(W3 + f0);
  }
  #pragma unroll
  for (int nt=0;nt<4;nt++){
    float p = 0.f;
    #pragma unroll
    for (int mt=0;mt<2;mt++){
      p += fmaxf(acc2[mt][nt][0]+b2v[mt].x,0.f)*w3v[mt].x;
      p += fmaxf(acc2[mt][nt][1]+b2v[mt].y,0.f)*w3v[mt].y;
      p += fmaxf(acc2[mt][nt][2]+b2v[mt].z,0.f)*w3v[mt].z;
      p += fmaxf(acc2[mt][nt][3]+b2v[mt].w,0.f)*w3v[mt].w;
    }
    p += __shfl_xor(p, 16);
    p += __shfl_xor(p, 32);
    if (lane < 16) atomicAdd(&Sedge[nt*16 + l15], p);
  }
  __syncthreads();
  // ---- loss + per-block graph reduction (block spans <=2 graphs) ----
  int gbase = n2g[ei[base]];
  if (tid < 64){
    int e = base + tid;
    float sv = Sedge[tid] + ob3[0] + dnoise[e];
    float l = 0.5f*sv*sv;
    int g = n2g[ei[e]] - gbase;     // in {0,1}
    atomicAdd(&part[g & 3], l);
  }
  __syncthreads();
  if (tid < 2 && (gbase + tid) < G)
    atomicAdd(&out[gbase + tid], part[tid]);
}

// =========================== host ===========================
static inline size_t alignup(size_t v){ return (v + 255) & ~(size_t)255; }

extern "C" void kernel_launch(void* const* d_in, const int* in_sizes, int n_in,
                              void* d_out, int out_size, void* d_ws, size_t ws_size,
                              hipStream_t stream) {
  const int*   at    = (const int*)  d_in[0];
  const int*   ei    = (const int*)  d_in[1];
  const int*   etype = (const int*)  d_in[2];
  const int*   n2g   = (const int*)  d_in[3];
  const int*   nl    = (const int*)  d_in[4];
  const float* pos   = (const float*)d_in[5];
  const float* dnoi  = (const float*)d_in[6];
  const float* sig   = (const float*)d_in[7];
  const float* nemb  = (const float*)d_in[8];
  const float* eemb  = (const float*)d_in[9];
  const float* inW1  = (const float*)d_in[10];
  const float* inb1  = (const float*)d_in[11];
  const float* inW2  = (const float*)d_in[12];
  const float* inb2  = (const float*)d_in[13];
  const float* gW1   = (const float*)d_in[14];
  const float* gb1   = (const float*)d_in[15];
  const float* gW2   = (const float*)d_in[16];
  const float* gb2   = (const float*)d_in[17];
  const float* oW1   = (const float*)d_in[18];
  const float* ob1   = (const float*)d_in[19];
  const float* oW2   = (const float*)d_in[20];
  const float* ob2   = (const float*)d_in[21];
  const float* oW3   = (const float*)d_in[22];
  const float* ob3   = (const float*)d_in[23];
  float* out = (float*)d_out;

  const int N = in_sizes[0];
  const int E = in_sizes[2];
  const int G = in_sizes[4];
  const int H = 256;

  char* w = (char*)d_ws;
  size_t off = 0;
  size_t o_attr  = off; off = alignup(off + (size_t)E*H*2);
  size_t o_xF    = off; off = alignup(off + (size_t)N*H*2);
  size_t o_pd    = off; off = alignup(off + (size_t)E*4);
  size_t o_cnt   = off; off = alignup(off + (size_t)N*4);
  size_t o_inl   = off; off = alignup(off + (size_t)N*8*4);
  size_t o_w2t   = off; off = alignup(off + (size_t)H*H*2);
  size_t o_gw1t  = off; off = alignup(off + (size_t)4*H*H*2);
  size_t o_gw2t  = off; off = alignup(off + (size_t)4*H*H*2);
  size_t o_ow1t  = off; off = alignup(off + (size_t)H*2*H*2);
  size_t o_ow2t  = off; off = alignup(off + (size_t)(H/2)*H*2);
  (void)ws_size; (void)n_in; (void)out_size;

  short* attrS = (short*)(w + o_attr);
  short* xF    = (short*)(w + o_xF);
  float* pd    = (float*)(w + o_pd);
  int*   cnt   = (int*)  (w + o_cnt);
  int*   inl   = (int*)  (w + o_inl);
  short* w2t   = (short*)(w + o_w2t);
  short* gw1t  = (short*)(w + o_gw1t);
  short* gw2t  = (short*)(w + o_gw2t);
  short* ow1t  = (short*)(w + o_ow1t);
  short* ow2t  = (short*)(w + o_ow2t);

  hipMemsetAsync(cnt, 0, (size_t)N*4, stream);
  hipMemsetAsync(out, 0, (size_t)G*4, stream);

  k_cvtAll<<<368, 256, 0, stream>>>(inW2, gW1, gW2, oW1, oW2,
                                    w2t, gw1t, gw2t, ow1t, ow2t);

  k_pre<<<(E+255)/256, 256, 0, stream>>>(ei, n2g, nl, sig, pos, dnoi, E, pd, cnt, inl);
  k_attr<<<E/64, 256, 0, stream>>>(pd, inW1, inb1, w2t, inb2, etype, eemb, attrS, E);

  k_conv4<<<G, 1024, 0, stream>>>(at, nemb, attrS, ei, cnt, inl,
                                  gw1t, gb1, gw2t, gb2, xF);

  k_head<<<E/64, 256, 0, stream>>>(xF, attrS, ei, ow1t, ob1, ow2t, ob2,
                                   oW3, ob3, dnoi, n2g, out, E, G);
}

// Round 16
// 531.503 us; speedup vs baseline: 1.1178x; 1.0067x over previous
//
#include <hip/hip_runtime.h>
#include <math.h>

typedef unsigned int u32;
typedef __attribute__((ext_vector_type(8))) short bf16x8;
typedef __attribute__((ext_vector_type(4))) float f32x4;

#define MFMA16(a,b,c) __builtin_amdgcn_mfma_f32_16x16x32_bf16(a,b,c,0,0,0)

// ---------- bf16 helpers ----------
__device__ inline u32 bf16r(float x){
  u32 u = __float_as_uint(x);
  return (u + 0x7fffu + ((u >> 16) & 1u)) >> 16;
}
__device__ inline u32 pack2(float a, float b){ return bf16r(a) | (bf16r(b) << 16); }
__device__ inline uint4 pack8(const float* f){
  uint4 v; v.x = pack2(f[0],f[1]); v.y = pack2(f[2],f[3]);
  v.z = pack2(f[4],f[5]); v.w = pack2(f[6],f[7]); return v;
}
__device__ inline float bf2f(short s){ return __uint_as_float(((u32)(unsigned short)s) << 16); }

// async global->LDS, 16B/lane; dest = wave-uniform base + lane*16 (src per-lane OK)
__device__ __forceinline__ void gload_lds16(const void* g, void* l){
  __builtin_amdgcn_global_load_lds((const __attribute__((address_space(1))) unsigned int*)g,
                                   (__attribute__((address_space(3))) unsigned int*)l,
                                   16, 0, 0);
}

// LDS fragment offset (shorts) in paired-macro-row granule layout
__device__ __forceinline__ int frag_off(int f, int quad){
  return (f>>1)*64 + (f&1)*32 + ((quad ^ ((f>>1)&3))*8);
}

// xls float4-granule swizzle (bank-verified for 32/16/8-ch thread maps)
__device__ __forceinline__ int xg(int g, int r){ return g ^ ((r ^ (g>>3)) & 7); }

// ---------- merged weight converter: f32 [K][Nf] -> bf16 row-major [Nf][K] ----------
__global__ void k_cvtAll(const float* __restrict__ inW2, const float* __restrict__ gW1,
                         const float* __restrict__ gW2, const float* __restrict__ oW1,
                         const float* __restrict__ oW2,
                         short* __restrict__ w2t, short* __restrict__ gw1t,
                         short* __restrict__ gw2t, short* __restrict__ ow1t,
                         short* __restrict__ ow2t){
  int gidx = blockIdx.x*256 + threadIdx.x;
  const float* src; short* dst; int t, K8, Nf;
  if (gidx < 8192)      { src = inW2; dst = w2t; t = gidx; K8 = 32; Nf = 256; }
  else if (gidx < 40960){ int r = gidx-8192;  int c = r>>13; t = r&8191;
                          src = gW1 + (size_t)c*65536; dst = gw1t + (size_t)c*65536; K8 = 32; Nf = 256; }
  else if (gidx < 73728){ int r = gidx-40960; int c = r>>13; t = r&8191;
                          src = gW2 + (size_t)c*65536; dst = gw2t + (size_t)c*65536; K8 = 32; Nf = 256; }
  else if (gidx < 90112){ t = gidx-73728; src = oW1; dst = ow1t; K8 = 64; Nf = 256; }
  else if (gidx < 94208){ t = gidx-90112; src = oW2; dst = ow2t; K8 = 32; Nf = 128; }
  else return;
  int f = t / K8, c = t - f*K8;
  float v[8];
  #pragma unroll
  for (int j=0;j<8;j++) v[j] = src[(size_t)(c*8+j)*Nf + f];
  ((uint4*)dst)[t] = pack8(v);
}

// ---------- per-edge scalars + CSR in-edge lists ----------
__global__ void k_pre(const int* __restrict__ ei, const int* __restrict__ n2g,
                      const int* __restrict__ nl, const float* __restrict__ sigmas,
                      const float* __restrict__ pos, const float* __restrict__ dn, int E,
                      float* __restrict__ pd, int* __restrict__ cnt, int* __restrict__ inlist){
  int e = blockIdx.x*256 + threadIdx.x;
  if (e >= E) return;
  int r = ei[e], c = ei[E+e];
  float sg = sigmas[nl[n2g[r]]];
  float dx = pos[3*r]-pos[3*c], dy = pos[3*r+1]-pos[3*c+1], dz = pos[3*r+2]-pos[3*c+2];
  float d = sqrtf(dx*dx + dy*dy + dz*dz);
  pd[e] = d + dn[e]*sg;
  int slot = atomicAdd(&cnt[c], 1);
  if (slot < 8) inlist[c*8 + slot] = e;
}

// ---------- edge_attr: barrier-free, no LDS. B computed in registers ----------
__global__ __launch_bounds__(256) void k_attr(
    const float* __restrict__ pd, const float* __restrict__ W1, const float* __restrict__ b1,
    const short* __restrict__ W2t, const float* __restrict__ b2,
    const int* __restrict__ etype, const float* __restrict__ eemb,
    short* __restrict__ attr, int E)
{
  int tid = threadIdx.x;
  int base = blockIdx.x*64;
  int wv = tid>>6, lane = tid&63, quad = lane>>4, l15 = lane&15;
  float pdv[4];
  #pragma unroll
  for (int nt=0;nt<4;nt++) pdv[nt] = pd[base + nt*16 + l15];
  f32x4 acc[4][4];
  #pragma unroll
  for (int mt=0;mt<4;mt++) for (int nt=0;nt<4;nt++) acc[mt][nt] = (f32x4)0.f;
  #pragma unroll
  for (int s=0; s<8; s++){
    int k0 = s*32 + quad*8;
    float4 w1a = *(const float4*)(W1 + k0), w1b = *(const float4*)(W1 + k0 + 4);
    float4 b1a = *(const float4*)(b1 + k0), b1b = *(const float4*)(b1 + k0 + 4);
    bf16x8 a[4], b[4];
    #pragma unroll
    for (int mt=0;mt<4;mt++){
      int f = (wv*4+mt)*16 + l15;
      a[mt] = *(const bf16x8*)(W2t + (size_t)f*256 + k0);
    }
    #pragma unroll
    for (int nt=0;nt<4;nt++){
      float p = pdv[nt];
      float f[8] = {fmaxf(p*w1a.x+b1a.x,0.f), fmaxf(p*w1a.y+b1a.y,0.f),
                    fmaxf(p*w1a.z+b1a.z,0.f), fmaxf(p*w1a.w+b1a.w,0.f),
                    fmaxf(p*w1b.x+b1b.x,0.f), fmaxf(p*w1b.y+b1b.y,0.f),
                    fmaxf(p*w1b.z+b1b.z,0.f), fmaxf(p*w1b.w+b1b.w,0.f)};
      uint4 u = pack8(f);
      b[nt] = *(bf16x8*)&u;
    }
    #pragma unroll
    for (int mt=0;mt<4;mt++)
      #pragma unroll
      for (int nt=0;nt<4;nt++)
        acc[mt][nt] = MFMA16(a[mt], b[nt], acc[mt][nt]);
  }
  #pragma unroll
  for (int nt=0;nt<4;nt++){
    int e = base + nt*16 + l15;
    int et = etype[e];
    #pragma unroll
    for (int mt=0;mt<4;mt++){
      int f0 = (wv*4+mt)*16 + quad*4;
      float4 bb = *(const float4*)(b2 + f0);
      float4 em = *(const float4*)(eemb + (size_t)et*256 + f0);
      float v0 = (acc[mt][nt][0]+bb.x)*em.x, v1 = (acc[mt][nt][1]+bb.y)*em.y;
      float v2 = (acc[mt][nt][2]+bb.z)*em.z, v3 = (acc[mt][nt][3]+bb.w)*em.w;
      uint2 v; v.x = pack2(v0,v1); v.y = pack2(v2,v3);
      *(uint2*)(attr + (size_t)e*256 + f0) = v;
    }
  }
}

// ---------- per-graph fused 4-conv kernel, 512 threads; fully-unrolled predicated gather ----------
// 1 block = 1 graph. attr staged once (92 KB); x in LDS fp32; T1 separate (3 barriers/conv).
#define EPG 180
__global__ __launch_bounds__(512,1) void k_conv4(
    const int* __restrict__ at, const float* __restrict__ nemb,
    const short* __restrict__ attrS, const int* __restrict__ ei,
    const int* __restrict__ cnt, const int* __restrict__ inlist,
    const short* __restrict__ gw1t, const float* __restrict__ gb1,
    const short* __restrict__ gw2t, const float* __restrict__ gb2,
    short* __restrict__ xF)
{
  __shared__ float xls[32*256];       // 32 KB
  __shared__ uint4 AlsV[32*32];       // 16 KB
  __shared__ uint4 T1V [32*32];       // 16 KB (separate: no barrier between GEMM1 and T1 write)
  __shared__ uint4 attrLV[EPG*32];    // 92160 B
  short* Als = (short*)AlsV;
  short* T1  = (short*)T1V;
  short* attrL = (short*)AlsV;        // placeholder; real attrL below
  attrL = (short*)attrLV;
  int tid = threadIdx.x;
  int nbase = blockIdx.x*32;
  int ebase = blockIdx.x*EPG;
  int wv = tid>>6, lane = tid&63, quad = lane>>4, l15 = lane&15;
  int jl = tid>>4, ch = tid&15;       // 16 threads/node, 16 feats each
  // ---- stage attr: 92160 B contiguous, 90 x 1024B wave-chunks ----
  {
    const char* src = (const char*)(attrS + (size_t)ebase*256) + lane*16;
    char* dst = (char*)attrLV;
    #pragma unroll
    for (int i=0; i<12; i++){
      int r = i*8 + wv;
      if (r < 90) gload_lds16(src + r*1024, dst + r*1024);
    }
  }
  // ---- topology: fully unrolled, constant-indexed (registers, no scratch) ----
  int deg;
  int eid[8], rl[8];
  {
    int j = nbase + jl;
    deg = min(cnt[j], 8);
    #pragma unroll
    for (int s=0;s<8;s++){
      int e = (s < deg) ? inlist[j*8 + s] : ebase;
      eid[s] = e - ebase;
      rl[s]  = (s < deg) ? (ei[e] - nbase) : 0;
    }
  }
  // ---- init xls from node_emb[at] ----
  {
    int a = at[nbase + jl];
    const float4* src = (const float4*)nemb + (size_t)a*64 + ch*4;
    float* xrow = xls + jl*256;
    #pragma unroll
    for (int q=0;q<4;q++)
      *(float4*)(xrow + (xg(ch*4+q, jl)<<2)) = src[q];
  }
  __syncthreads();   // drains gloads (vmcnt) + ds writes
  for (int c=0; c<4; c++){
    const short* W1t = gw1t + (size_t)c*65536;
    const short* W2t = gw2t + (size_t)c*65536;
    const float* b1 = gb1 + c*256;
    const float* b2 = gb2 + c*256;
    // ---- gather staging into Als: hin[j] = x[j] + sum relu(x[r]+attr[e]) ----
    // FULLY UNROLLED: all neighbor loads are independent -> pipelined under one waitcnt
    {
      float f[16];
      const float* xrow = xls + jl*256;
      #pragma unroll
      for (int q=0;q<4;q++){
        float4 v = *(const float4*)(xrow + (xg(ch*4+q, jl)<<2));
        f[q*4]=v.x; f[q*4+1]=v.y; f[q*4+2]=v.z; f[q*4+3]=v.w;
      }
      #pragma unroll
      for (int s=0; s<8; s++){
        if (s < deg){
          int r = rl[s];
          const float* xr = xls + r*256;
          const short* ar = attrL + eid[s]*256 + ch*16;
          #pragma unroll
          for (int q=0;q<4;q++){
            float4 xv = *(const float4*)(xr + (xg(ch*4+q, r)<<2));
            uint2 a2 = *(const uint2*)(ar + q*4);
            f[q*4]   += fmaxf(xv.x + __uint_as_float(a2.x<<16), 0.f);
            f[q*4+1] += fmaxf(xv.y + __uint_as_float(a2.x&0xffff0000u), 0.f);
            f[q*4+2] += fmaxf(xv.z + __uint_as_float(a2.y<<16), 0.f);
            f[q*4+3] += fmaxf(xv.w + __uint_as_float(a2.y&0xffff0000u), 0.f);
          }
        }
      }
      #pragma unroll
      for (int qq=0;qq<2;qq++){
        int cc = ch*2 + qq;
        *(uint4*)(Als + jl*256 + ((cc ^ (jl&7))*8)) = pack8(f + qq*8);
      }
    }
    __syncthreads();
    // ---- GEMM1: M=256 (8 waves x 32 feats), N=32, K=256; A direct from L2 ----
    f32x4 acc[2][2];
    #pragma unroll
    for (int mt=0;mt<2;mt++) for (int nt=0;nt<2;nt++) acc[mt][nt] = (f32x4)0.f;
    #pragma unroll
    for (int s=0; s<8; s++){
      bf16x8 a[2], b[2];
      #pragma unroll
      for (int mt=0;mt<2;mt++)
        a[mt] = *(const bf16x8*)(W1t + (size_t)((wv*2+mt)*16 + l15)*256 + s*32 + quad*8);
      #pragma unroll
      for (int nt=0;nt<2;nt++){
        int n = nt*16 + l15; int cc = s*4 + quad;
        b[nt] = *(const bf16x8*)(Als + n*256 + ((cc ^ (n&7))*8));
      }
      #pragma unroll
      for (int mt=0;mt<2;mt++)
        #pragma unroll
        for (int nt=0;nt<2;nt++)
          acc[mt][nt] = MFMA16(a[mt], b[nt], acc[mt][nt]);
    }
    // T1 separate buffer: write immediately (depends only on registers)
    #pragma unroll
    for (int mt=0;mt<2;mt++){
      int f0 = (wv*2+mt)*16 + quad*4;
      float4 bb = *(const float4*)(b1 + f0);
      int cg = f0 >> 3, off = (quad&1)*4;
      #pragma unroll
      for (int nt=0;nt<2;nt++){
        int n = nt*16 + l15;
        float v0 = fmaxf(acc[mt][nt][0]+bb.x,0.f), v1 = fmaxf(acc[mt][nt][1]+bb.y,0.f);
        float v2 = fmaxf(acc[mt][nt][2]+bb.z,0.f), v3 = fmaxf(acc[mt][nt][3]+bb.w,0.f);
        uint2 v; v.x = pack2(v0,v1); v.y = pack2(v2,v3);
        *(uint2*)(T1 + n*256 + ((cg ^ (n&7))*8) + off) = v;
      }
    }
    __syncthreads();
    // ---- GEMM2 ----
    f32x4 acc2[2][2];
    #pragma unroll
    for (int mt=0;mt<2;mt++) for (int nt=0;nt<2;nt++) acc2[mt][nt] = (f32x4)0.f;
    #pragma unroll
    for (int s=0; s<8; s++){
      bf16x8 a[2], b[2];
      #pragma unroll
      for (int mt=0;mt<2;mt++)
        a[mt] = *(const bf16x8*)(W2t + (size_t)((wv*2+mt)*16 + l15)*256 + s*32 + quad*8);
      #pragma unroll
      for (int nt=0;nt<2;nt++){
        int n = nt*16 + l15; int cc = s*4 + quad;
        b[nt] = *(const bf16x8*)(T1 + n*256 + ((cc ^ (n&7))*8));
      }
      #pragma unroll
      for (int mt=0;mt<2;mt++)
        #pragma unroll
        for (int nt=0;nt<2;nt++)
          acc2[mt][nt] = MFMA16(a[mt], b[nt], acc2[mt][nt]);
    }
    // ---- residual update into xls (relu for c<3) ----
    #pragma unroll
    for (int mt=0;mt<2;mt++){
      int f0 = (wv*2+mt)*16 + quad*4;
      float4 bb = *(const float4*)(b2 + f0);
      int g = f0 >> 2;
      #pragma unroll
      for (int nt=0;nt<2;nt++){
        int n = nt*16 + l15;
        float* px = xls + n*256 + (xg(g, n)<<2);
        float4 xv = *(float4*)px;
        float h0 = acc2[mt][nt][0]+bb.x, h1 = acc2[mt][nt][1]+bb.y;
        float h2 = acc2[mt][nt][2]+bb.z, h3 = acc2[mt][nt][3]+bb.w;
        if (c < 3){ h0=fmaxf(h0,0.f); h1=fmaxf(h1,0.f); h2=fmaxf(h2,0.f); h3=fmaxf(h3,0.f); }
        xv.x += h0; xv.y += h1; xv.z += h2; xv.w += h3;
        *(float4*)px = xv;
      }
    }
    __syncthreads();   // xls updates visible before next gather / writeout
  }
  // ---- writeout xF (bf16, row-major) ----
  {
    const float* xrow = xls + jl*256;
    float f[16];
    #pragma unroll
    for (int q=0;q<4;q++){
      float4 v = *(const float4*)(xrow + (xg(ch*4+q, jl)<<2));
      f[q*4]=v.x; f[q*4+1]=v.y; f[q*4+2]=v.z; f[q*4+3]=v.w;
    }
    #pragma unroll
    for (int qq=0;qq<2;qq++)
      *(uint4*)(xF + (size_t)(nbase+jl)*256 + ch*16 + qq*8) = pack8(f + qq*8);
  }
}

// ---------- fully fused head: L1 GEMM -> T(LDS) -> L2 GEMM -> L3 dot -> loss reduce ----------
// 64 edges/block; x is bf16; 2 global atomics/block
__global__ __launch_bounds__(256,2) void k_head(
    const short* __restrict__ xF, const short* __restrict__ attrS,
    const int* __restrict__ ei,
    const short* __restrict__ W1t, const float* __restrict__ ob1,
    const short* __restrict__ W2t, const float* __restrict__ ob2,
    const float* __restrict__ W3, const float* __restrict__ ob3,
    const float* __restrict__ dnoise, const int* __restrict__ n2g,
    float* __restrict__ out, int E, int G)
{
  __shared__ uint4 BlsV[16*256];   // 64 KB; T (32 KB) aliases after L1
  __shared__ float Sedge[64];
  __shared__ float part[4];
  short* Bls = (short*)BlsV;
  short* T   = (short*)BlsV;
  int tid = threadIdx.x;
  int base = blockIdx.x*64;
  int wv = tid>>6, lane = tid&63, quad = lane>>4, l15 = lane&15;
  if (tid < 64) Sedge[tid] = 0.f;
  if (tid < 4) part[tid] = 0.f;
  // attr slices (s=8..15): per-lane-source gload
  {
    int g = wv*64 + lane;
    int p = g>>3, hi = (g>>2)&1, cs = g&3;
    int n = p*2 + hi, cc = cs ^ (p&3);
    const short* srcb = attrS + (size_t)(base+n)*256 + cc*8;
    #pragma unroll
    for (int s=8; s<16; s++)
      gload_lds16(srcb + (s-8)*32, (char*)Bls + (size_t)s*4096 + wv*1024);
  }
  // xr*xc slices (s=0..7), bf16 inputs
  {
    int g = tid;
    int p = g>>3, hi = (g>>2)&1, cs = g&3;
    int n = p*2 + hi, cc = cs ^ (p&3);
    int rr = ei[base+n], rc = ei[E+base+n];
    const short* xr = xF + (size_t)rr*256 + cc*8;
    const short* xc = xF + (size_t)rc*256 + cc*8;
    #pragma unroll
    for (int s=0; s<8; s++){
      bf16x8 va = *(const bf16x8*)(xr + s*32);
      bf16x8 vb = *(const bf16x8*)(xc + s*32);
      float f[8];
      #pragma unroll
      for (int j=0;j<8;j++) f[j] = bf2f(va[j])*bf2f(vb[j]);
      *(uint4*)(Bls + (size_t)s*2048 + g*8) = pack8(f);
    }
  }
  __syncthreads();
  // ---- L1: 16 barrier-free K-slices; M=256, N=64 ----
  f32x4 acc[4][4];
  #pragma unroll
  for (int mt=0;mt<4;mt++) for (int nt=0;nt<4;nt++) acc[mt][nt] = (f32x4)0.f;
  #pragma unroll
  for (int s=0; s<16; s++){
    bf16x8 a[4], b[4];
    #pragma unroll
    for (int mt=0;mt<4;mt++)
      a[mt] = *(const bf16x8*)(W1t + (size_t)((wv*4+mt)*16 + l15)*512 + s*32 + quad*8);
    #pragma unroll
    for (int nt=0;nt<4;nt++)
      b[nt] = *(const bf16x8*)(Bls + (size_t)s*2048 + frag_off(nt*16 + l15, quad));
    #pragma unroll
    for (int mt=0;mt<4;mt++)
      #pragma unroll
      for (int nt=0;nt<4;nt++)
        acc[mt][nt] = MFMA16(a[mt], b[nt], acc[mt][nt]);
  }
  __syncthreads();   // all waves done reading Bls; T aliases it
  #pragma unroll
  for (int mt=0;mt<4;mt++){
    int f0 = (wv*4+mt)*16 + quad*4;
    float4 bb = *(const float4*)(ob1 + f0);
    int c = f0 >> 3, off = (quad&1)*4;
    #pragma unroll
    for (int nt=0;nt<4;nt++){
      int n = nt*16 + l15;
      float v0 = fmaxf(acc[mt][nt][0]+bb.x,0.f), v1 = fmaxf(acc[mt][nt][1]+bb.y,0.f);
      float v2 = fmaxf(acc[mt][nt][2]+bb.z,0.f), v3 = fmaxf(acc[mt][nt][3]+bb.w,0.f);
      uint2 v; v.x = pack2(v0,v1); v.y = pack2(v2,v3);
      *(uint2*)(T + n*256 + ((c ^ (n&7))*8) + off) = v;
    }
  }
  __syncthreads();
  // ---- L2: 8 barrier-free K-slices; M=128, N=64; A direct (L2-hot) ----
  f32x4 acc2[2][4];
  #pragma unroll
  for (int mt=0;mt<2;mt++) for (int nt=0;nt<4;nt++) acc2[mt][nt] = (f32x4)0.f;
  #pragma unroll
  for (int s=0; s<8; s++){
    bf16x8 a[2], b[4];
    #pragma unroll
    for (int mt=0;mt<2;mt++)
      a[mt] = *(const bf16x8*)(W2t + (size_t)((wv*2+mt)*16 + l15)*256 + s*32 + quad*8);
    #pragma unroll
    for (int nt=0;nt<4;nt++){
      int n = nt*16 + l15; int cc = s*4 + quad;
      b[nt] = *(const bf16x8*)(T + n*256 + ((cc ^ (n&7))*8));
    }
    #pragma unroll
    for (int mt=0;mt<2;mt++)
      #pragma unroll
      for (int nt=0;nt<4;nt++)
        acc2[mt][nt] = MFMA16(a[mt], b[nt], acc2[mt][nt]);
  }
  // ---- L3 dot + cross-wave per-edge reduce ----
  float4 b2v[2], w3v[2];
  #pragma unroll
  for (int mt=0;mt<2;mt++){
    int f0 = (wv*2+mt)*16 + quad*4;
    b2v[mt] = *(const float4*)(ob2 + f0);
    w3v[mt] = *(const float4*)(W3 + f0);
  }
  #pragma unroll
  for (int nt=0;nt<4;nt++){
    float p = 0.f;
    #pragma unroll
    for (int mt=0;mt<2;mt++){
      p += fmaxf(acc2[mt][nt][0]+b2v[mt].x,0.f)*w3v[mt].x;
      p += fmaxf(acc2[mt][nt][1]+b2v[mt].y,0.f)*w3v[mt].y;
      p += fmaxf(acc2[mt][nt][2]+b2v[mt].z,0.f)*w3v[mt].z;
      p += fmaxf(acc2[mt][nt][3]+b2v[mt].w,0.f)*w3v[mt].w;
    }
    p += __shfl_xor(p, 16);
    p += __shfl_xor(p, 32);
    if (lane < 16) atomicAdd(&Sedge[nt*16 + l15], p);
  }
  __syncthreads();
  // ---- loss + per-block graph reduction (block spans <=2 graphs) ----
  int gbase = n2g[ei[base]];
  if (tid < 64){
    int e = base + tid;
    float sv = Sedge[tid] + ob3[0] + dnoise[e];
    float l = 0.5f*sv*sv;
    int g = n2g[ei[e]] - gbase;     // in {0,1}
    atomicAdd(&part[g & 3], l);
  }
  __syncthreads();
  if (tid < 2 && (gbase + tid) < G)
    atomicAdd(&out[gbase + tid], part[tid]);
}

// =========================== host ===========================
static inline size_t alignup(size_t v){ return (v + 255) & ~(size_t)255; }

extern "C" void kernel_launch(void* const* d_in, const int* in_sizes, int n_in,
                              void* d_out, int out_size, void* d_ws, size_t ws_size,
                              hipStream_t stream) {
  const int*   at    = (const int*)  d_in[0];
  const int*   ei    = (const int*)  d_in[1];
  const int*   etype = (const int*)  d_in[2];
  const int*   n2g   = (const int*)  d_in[3];
  const int*   nl    = (const int*)  d_in[4];
  const float* pos   = (const float*)d_in[5];
  const float* dnoi  = (const float*)d_in[6];
  const float* sig   = (const float*)d_in[7];
  const float* nemb  = (const float*)d_in[8];
  const float* eemb  = (const float*)d_in[9];
  const float* inW1  = (const float*)d_in[10];
  const float* inb1  = (const float*)d_in[11];
  const float* inW2  = (const float*)d_in[12];
  const float* inb2  = (const float*)d_in[13];
  const float* gW1   = (const float*)d_in[14];
  const float* gb1   = (const float*)d_in[15];
  const float* gW2   = (const float*)d_in[16];
  const float* gb2   = (const float*)d_in[17];
  const float* oW1   = (const float*)d_in[18];
  const float* ob1   = (const float*)d_in[19];
  const float* oW2   = (const float*)d_in[20];
  const float* ob2   = (const float*)d_in[21];
  const float* oW3   = (const float*)d_in[22];
  const float* ob3   = (const float*)d_in[23];
  float* out = (float*)d_out;

  const int N = in_sizes[0];
  const int E = in_sizes[2];
  const int G = in_sizes[4];
  const int H = 256;

  char* w = (char*)d_ws;
  size_t off = 0;
  size_t o_attr  = off; off = alignup(off + (size_t)E*H*2);
  size_t o_xF    = off; off = alignup(off + (size_t)N*H*2);
  size_t o_pd    = off; off = alignup(off + (size_t)E*4);
  size_t o_cnt   = off; off = alignup(off + (size_t)N*4);
  size_t o_inl   = off; off = alignup(off + (size_t)N*8*4);
  size_t o_w2t   = off; off = alignup(off + (size_t)H*H*2);
  size_t o_gw1t  = off; off = alignup(off + (size_t)4*H*H*2);
  size_t o_gw2t  = off; off = alignup(off + (size_t)4*H*H*2);
  size_t o_ow1t  = off; off = alignup(off + (size_t)H*2*H*2);
  size_t o_ow2t  = off; off = alignup(off + (size_t)(H/2)*H*2);
  (void)ws_size; (void)n_in; (void)out_size;

  short* attrS = (short*)(w + o_attr);
  short* xF    = (short*)(w + o_xF);
  float* pd    = (float*)(w + o_pd);
  int*   cnt   = (int*)  (w + o_cnt);
  int*   inl   = (int*)  (w + o_inl);
  short* w2t   = (short*)(w + o_w2t);
  short* gw1t  = (short*)(w + o_gw1t);
  short* gw2t  = (short*)(w + o_gw2t);
  short* ow1t  = (short*)(w + o_ow1t);
  short* ow2t  = (short*)(w + o_ow2t);

  hipMemsetAsync(cnt, 0, (size_t)N*4, stream);
  hipMemsetAsync(out, 0, (size_t)G*4, stream);

  k_cvtAll<<<368, 256, 0, stream>>>(inW2, gW1, gW2, oW1, oW2,
                                    w2t, gw1t, gw2t, ow1t, ow2t);

  k_pre<<<(E+255)/256, 256, 0, stream>>>(ei, n2g, nl, sig, pos, dnoi, E, pd, cnt, inl);
  k_attr<<<E/64, 256, 0, stream>>>(pd, inW1, inb1, w2t, inb2, etype, eemb, attrS, E);

  k_conv4<<<G, 512, 0, stream>>>(at, nemb, attrS, ei, cnt, inl,
                                 gw1t, gb1, gw2t, gb2, xF);

  k_head<<<E/64, 256, 0, stream>>>(xF, attrS, ei, ow1t, ob1, ow2t, ob2,
                                   oW3, ob3, dnoi, n2g, out, E, G);
}

// Round 17
// 507.000 us; speedup vs baseline: 1.1718x; 1.0483x over previous
//
#include <hip/hip_runtime.h>
#include <math.h>

typedef unsigned int u32;
typedef __attribute__((ext_vector_type(8))) short bf16x8;
typedef __attribute__((ext_vector_type(4))) float f32x4;

#define MFMA16(a,b,c) __builtin_amdgcn_mfma_f32_16x16x32_bf16(a,b,c,0,0,0)

// ---------- bf16 helpers ----------
__device__ inline u32 bf16r(float x){
  u32 u = __float_as_uint(x);
  return (u + 0x7fffu + ((u >> 16) & 1u)) >> 16;
}
__device__ inline u32 pack2(float a, float b){ return bf16r(a) | (bf16r(b) << 16); }
__device__ inline uint4 pack8(const float* f){
  uint4 v; v.x = pack2(f[0],f[1]); v.y = pack2(f[2],f[3]);
  v.z = pack2(f[4],f[5]); v.w = pack2(f[6],f[7]); return v;
}
__device__ inline float bf2f(short s){ return __uint_as_float(((u32)(unsigned short)s) << 16); }

// async global->LDS, 16B/lane; dest = wave-uniform base + lane*16 (src per-lane OK)
__device__ __forceinline__ void gload_lds16(const void* g, void* l){
  __builtin_amdgcn_global_load_lds((const __attribute__((address_space(1))) unsigned int*)g,
                                   (__attribute__((address_space(3))) unsigned int*)l,
                                   16, 0, 0);
}

// LDS fragment offset (shorts) in paired-macro-row granule layout
__device__ __forceinline__ int frag_off(int f, int quad){
  return (f>>1)*64 + (f&1)*32 + ((quad ^ ((f>>1)&3))*8);
}

// xls float4-granule swizzle (bank-verified for 32/16/8-ch thread maps)
__device__ __forceinline__ int xg(int g, int r){ return g ^ ((r ^ (g>>3)) & 7); }

// ---------- merged weight converter: f32 [K][Nf] -> bf16 row-major [Nf][K] ----------
__global__ void k_cvtAll(const float* __restrict__ inW2, const float* __restrict__ gW1,
                         const float* __restrict__ gW2, const float* __restrict__ oW1,
                         const float* __restrict__ oW2,
                         short* __restrict__ w2t, short* __restrict__ gw1t,
                         short* __restrict__ gw2t, short* __restrict__ ow1t,
                         short* __restrict__ ow2t){
  int gidx = blockIdx.x*256 + threadIdx.x;
  const float* src; short* dst; int t, K8, Nf;
  if (gidx < 8192)      { src = inW2; dst = w2t; t = gidx; K8 = 32; Nf = 256; }
  else if (gidx < 40960){ int r = gidx-8192;  int c = r>>13; t = r&8191;
                          src = gW1 + (size_t)c*65536; dst = gw1t + (size_t)c*65536; K8 = 32; Nf = 256; }
  else if (gidx < 73728){ int r = gidx-40960; int c = r>>13; t = r&8191;
                          src = gW2 + (size_t)c*65536; dst = gw2t + (size_t)c*65536; K8 = 32; Nf = 256; }
  else if (gidx < 90112){ t = gidx-73728; src = oW1; dst = ow1t; K8 = 64; Nf = 256; }
  else if (gidx < 94208){ t = gidx-90112; src = oW2; dst = ow2t; K8 = 32; Nf = 128; }
  else return;
  int f = t / K8, c = t - f*K8;
  float v[8];
  #pragma unroll
  for (int j=0;j<8;j++) v[j] = src[(size_t)(c*8+j)*Nf + f];
  ((uint4*)dst)[t] = pack8(v);
}

// ---------- per-edge scalars + CSR in-edge lists ----------
__global__ void k_pre(const int* __restrict__ ei, const int* __restrict__ n2g,
                      const int* __restrict__ nl, const float* __restrict__ sigmas,
                      const float* __restrict__ pos, const float* __restrict__ dn, int E,
                      float* __restrict__ pd, int* __restrict__ cnt, int* __restrict__ inlist){
  int e = blockIdx.x*256 + threadIdx.x;
  if (e >= E) return;
  int r = ei[e], c = ei[E+e];
  float sg = sigmas[nl[n2g[r]]];
  float dx = pos[3*r]-pos[3*c], dy = pos[3*r+1]-pos[3*c+1], dz = pos[3*r+2]-pos[3*c+2];
  float d = sqrtf(dx*dx + dy*dy + dz*dz);
  pd[e] = d + dn[e]*sg;
  int slot = atomicAdd(&cnt[c], 1);
  if (slot < 8) inlist[c*8 + slot] = e;
}

// ---------- edge_attr: barrier-free, no LDS. B computed in registers ----------
__global__ __launch_bounds__(256) void k_attr(
    const float* __restrict__ pd, const float* __restrict__ W1, const float* __restrict__ b1,
    const short* __restrict__ W2t, const float* __restrict__ b2,
    const int* __restrict__ etype, const float* __restrict__ eemb,
    short* __restrict__ attr, int E)
{
  int tid = threadIdx.x;
  int base = blockIdx.x*64;
  int wv = tid>>6, lane = tid&63, quad = lane>>4, l15 = lane&15;
  float pdv[4];
  #pragma unroll
  for (int nt=0;nt<4;nt++) pdv[nt] = pd[base + nt*16 + l15];
  f32x4 acc[4][4];
  #pragma unroll
  for (int mt=0;mt<4;mt++) for (int nt=0;nt<4;nt++) acc[mt][nt] = (f32x4)0.f;
  #pragma unroll
  for (int s=0; s<8; s++){
    int k0 = s*32 + quad*8;
    float4 w1a = *(const float4*)(W1 + k0), w1b = *(const float4*)(W1 + k0 + 4);
    float4 b1a = *(const float4*)(b1 + k0), b1b = *(const float4*)(b1 + k0 + 4);
    bf16x8 a[4], b[4];
    #pragma unroll
    for (int mt=0;mt<4;mt++){
      int f = (wv*4+mt)*16 + l15;
      a[mt] = *(const bf16x8*)(W2t + (size_t)f*256 + k0);
    }
    #pragma unroll
    for (int nt=0;nt<4;nt++){
      float p = pdv[nt];
      float f[8] = {fmaxf(p*w1a.x+b1a.x,0.f), fmaxf(p*w1a.y+b1a.y,0.f),
                    fmaxf(p*w1a.z+b1a.z,0.f), fmaxf(p*w1a.w+b1a.w,0.f),
                    fmaxf(p*w1b.x+b1b.x,0.f), fmaxf(p*w1b.y+b1b.y,0.f),
                    fmaxf(p*w1b.z+b1b.z,0.f), fmaxf(p*w1b.w+b1b.w,0.f)};
      uint4 u = pack8(f);
      b[nt] = *(bf16x8*)&u;
    }
    #pragma unroll
    for (int mt=0;mt<4;mt++)
      #pragma unroll
      for (int nt=0;nt<4;nt++)
        acc[mt][nt] = MFMA16(a[mt], b[nt], acc[mt][nt]);
  }
  #pragma unroll
  for (int nt=0;nt<4;nt++){
    int e = base + nt*16 + l15;
    int et = etype[e];
    #pragma unroll
    for (int mt=0;mt<4;mt++){
      int f0 = (wv*4+mt)*16 + quad*4;
      float4 bb = *(const float4*)(b2 + f0);
      float4 em = *(const float4*)(eemb + (size_t)et*256 + f0);
      float v0 = (acc[mt][nt][0]+bb.x)*em.x, v1 = (acc[mt][nt][1]+bb.y)*em.y;
      float v2 = (acc[mt][nt][2]+bb.z)*em.z, v3 = (acc[mt][nt][3]+bb.w)*em.w;
      uint2 v; v.x = pack2(v0,v1); v.y = pack2(v2,v3);
      *(uint2*)(attr + (size_t)e*256 + f0) = v;
    }
  }
}

// ---------- per-graph fused 4-conv kernel, 512 threads, 64 KB LDS -> 2 blocks/CU ----------
// attr read direct from global (L3) with unrolled independent loads; cross-block TLP hides latency.
__global__ __launch_bounds__(512,2) void k_conv4(
    const int* __restrict__ at, const float* __restrict__ nemb,
    const short* __restrict__ attrS, const int* __restrict__ ei,
    const int* __restrict__ cnt, const int* __restrict__ inlist,
    const short* __restrict__ gw1t, const float* __restrict__ gb1,
    const short* __restrict__ gw2t, const float* __restrict__ gb2,
    short* __restrict__ xF)
{
  __shared__ float xls[32*256];       // 32 KB
  __shared__ uint4 AlsV[32*32];       // 16 KB
  __shared__ uint4 T1V [32*32];       // 16 KB
  short* Als = (short*)AlsV;
  short* T1  = (short*)T1V;
  int tid = threadIdx.x;
  int nbase = blockIdx.x*32;
  int wv = tid>>6, lane = tid&63, quad = lane>>4, l15 = lane&15;
  int jl = tid>>4, ch = tid&15;       // 16 threads/node, 16 feats each
  // ---- topology: fully unrolled, constant-indexed (registers) ----
  int deg;
  int eid[8], rl[8];
  {
    int j = nbase + jl;
    deg = min(cnt[j], 8);
    #pragma unroll
    for (int s=0;s<8;s++){
      int e = (s < deg) ? inlist[j*8 + s] : 0;
      eid[s] = e;
      rl[s]  = (s < deg) ? (ei[e] - nbase) : 0;
    }
  }
  // ---- init xls from node_emb[at] ----
  {
    int a = at[nbase + jl];
    const float4* src = (const float4*)nemb + (size_t)a*64 + ch*4;
    float* xrow = xls + jl*256;
    #pragma unroll
    for (int q=0;q<4;q++)
      *(float4*)(xrow + (xg(ch*4+q, jl)<<2)) = src[q];
  }
  __syncthreads();
  for (int c=0; c<4; c++){
    const short* W1t = gw1t + (size_t)c*65536;
    const short* W2t = gw2t + (size_t)c*65536;
    const float* b1 = gb1 + c*256;
    const float* b2 = gb2 + c*256;
    // ---- gather staging into Als: hin[j] = x[j] + sum relu(x[r]+attr[e]) ----
    // attr loads direct from global: unrolled, independent -> pipelined under vmcnt
    {
      float f[16];
      const float* xrow = xls + jl*256;
      #pragma unroll
      for (int q=0;q<4;q++){
        float4 v = *(const float4*)(xrow + (xg(ch*4+q, jl)<<2));
        f[q*4]=v.x; f[q*4+1]=v.y; f[q*4+2]=v.z; f[q*4+3]=v.w;
      }
      #pragma unroll
      for (int s=0; s<8; s++){
        if (s < deg){
          int r = rl[s];
          const float* xr = xls + r*256;
          const short* ar = attrS + (size_t)eid[s]*256 + ch*16;
          uint4 a4a = *(const uint4*)(ar);
          uint4 a4b = *(const uint4*)(ar + 8);
          u32 us[8] = {a4a.x,a4a.y,a4a.z,a4a.w, a4b.x,a4b.y,a4b.z,a4b.w};
          #pragma unroll
          for (int q=0;q<4;q++){
            float4 xv = *(const float4*)(xr + (xg(ch*4+q, r)<<2));
            u32 lo = us[2*q], hi = us[2*q+1];
            f[q*4]   += fmaxf(xv.x + __uint_as_float(lo<<16), 0.f);
            f[q*4+1] += fmaxf(xv.y + __uint_as_float(lo&0xffff0000u), 0.f);
            f[q*4+2] += fmaxf(xv.z + __uint_as_float(hi<<16), 0.f);
            f[q*4+3] += fmaxf(xv.w + __uint_as_float(hi&0xffff0000u), 0.f);
          }
        }
      }
      #pragma unroll
      for (int qq=0;qq<2;qq++){
        int cc = ch*2 + qq;
        *(uint4*)(Als + jl*256 + ((cc ^ (jl&7))*8)) = pack8(f + qq*8);
      }
    }
    __syncthreads();
    // ---- GEMM1: M=256 (8 waves x 32 feats), N=32, K=256; A direct from L2 ----
    f32x4 acc[2][2];
    #pragma unroll
    for (int mt=0;mt<2;mt++) for (int nt=0;nt<2;nt++) acc[mt][nt] = (f32x4)0.f;
    #pragma unroll
    for (int s=0; s<8; s++){
      bf16x8 a[2], b[2];
      #pragma unroll
      for (int mt=0;mt<2;mt++)
        a[mt] = *(const bf16x8*)(W1t + (size_t)((wv*2+mt)*16 + l15)*256 + s*32 + quad*8);
      #pragma unroll
      for (int nt=0;nt<2;nt++){
        int n = nt*16 + l15; int cc = s*4 + quad;
        b[nt] = *(const bf16x8*)(Als + n*256 + ((cc ^ (n&7))*8));
      }
      #pragma unroll
      for (int mt=0;mt<2;mt++)
        #pragma unroll
        for (int nt=0;nt<2;nt++)
          acc[mt][nt] = MFMA16(a[mt], b[nt], acc[mt][nt]);
    }
    // T1 separate buffer: write immediately (register-dependent only)
    #pragma unroll
    for (int mt=0;mt<2;mt++){
      int f0 = (wv*2+mt)*16 + quad*4;
      float4 bb = *(const float4*)(b1 + f0);
      int cg = f0 >> 3, off = (quad&1)*4;
      #pragma unroll
      for (int nt=0;nt<2;nt++){
        int n = nt*16 + l15;
        float v0 = fmaxf(acc[mt][nt][0]+bb.x,0.f), v1 = fmaxf(acc[mt][nt][1]+bb.y,0.f);
        float v2 = fmaxf(acc[mt][nt][2]+bb.z,0.f), v3 = fmaxf(acc[mt][nt][3]+bb.w,0.f);
        uint2 v; v.x = pack2(v0,v1); v.y = pack2(v2,v3);
        *(uint2*)(T1 + n*256 + ((cg ^ (n&7))*8) + off) = v;
      }
    }
    __syncthreads();
    // ---- GEMM2 ----
    f32x4 acc2[2][2];
    #pragma unroll
    for (int mt=0;mt<2;mt++) for (int nt=0;nt<2;nt++) acc2[mt][nt] = (f32x4)0.f;
    #pragma unroll
    for (int s=0; s<8; s++){
      bf16x8 a[2], b[2];
      #pragma unroll
      for (int mt=0;mt<2;mt++)
        a[mt] = *(const bf16x8*)(W2t + (size_t)((wv*2+mt)*16 + l15)*256 + s*32 + quad*8);
      #pragma unroll
      for (int nt=0;nt<2;nt++){
        int n = nt*16 + l15; int cc = s*4 + quad;
        b[nt] = *(const bf16x8*)(T1 + n*256 + ((cc ^ (n&7))*8));
      }
      #pragma unroll
      for (int mt=0;mt<2;mt++)
        #pragma unroll
        for (int nt=0;nt<2;nt++)
          acc2[mt][nt] = MFMA16(a[mt], b[nt], acc2[mt][nt]);
    }
    // ---- residual update into xls (relu for c<3) ----
    #pragma unroll
    for (int mt=0;mt<2;mt++){
      int f0 = (wv*2+mt)*16 + quad*4;
      float4 bb = *(const float4*)(b2 + f0);
      int g = f0 >> 2;
      #pragma unroll
      for (int nt=0;nt<2;nt++){
        int n = nt*16 + l15;
        float* px = xls + n*256 + (xg(g, n)<<2);
        float4 xv = *(float4*)px;
        float h0 = acc2[mt][nt][0]+bb.x, h1 = acc2[mt][nt][1]+bb.y;
        float h2 = acc2[mt][nt][2]+bb.z, h3 = acc2[mt][nt][3]+bb.w;
        if (c < 3){ h0=fmaxf(h0,0.f); h1=fmaxf(h1,0.f); h2=fmaxf(h2,0.f); h3=fmaxf(h3,0.f); }
        xv.x += h0; xv.y += h1; xv.z += h2; xv.w += h3;
        *(float4*)px = xv;
      }
    }
    __syncthreads();   // xls updates visible before next gather / writeout
  }
  // ---- writeout xF (bf16, row-major) ----
  {
    const float* xrow = xls + jl*256;
    float f[16];
    #pragma unroll
    for (int q=0;q<4;q++){
      float4 v = *(const float4*)(xrow + (xg(ch*4+q, jl)<<2));
      f[q*4]=v.x; f[q*4+1]=v.y; f[q*4+2]=v.z; f[q*4+3]=v.w;
    }
    #pragma unroll
    for (int qq=0;qq<2;qq++)
      *(uint4*)(xF + (size_t)(nbase+jl)*256 + ch*16 + qq*8) = pack8(f + qq*8);
  }
}

// ---------- fully fused head: L1 GEMM -> T(LDS) -> L2 GEMM -> L3 dot -> loss reduce ----------
// 64 edges/block; x is bf16; 2 global atomics/block
__global__ __launch_bounds__(256,2) void k_head(
    const short* __restrict__ xF, const short* __restrict__ attrS,
    const int* __restrict__ ei,
    const short* __restrict__ W1t, const float* __restrict__ ob1,
    const short* __restrict__ W2t, const float* __restrict__ ob2,
    const float* __restrict__ W3, const float* __restrict__ ob3,
    const float* __restrict__ dnoise, const int* __restrict__ n2g,
    float* __restrict__ out, int E, int G)
{
  __shared__ uint4 BlsV[16*256];   // 64 KB; T (32 KB) aliases after L1
  __shared__ float Sedge[64];
  __shared__ float part[4];
  short* Bls = (short*)BlsV;
  short* T   = (short*)BlsV;
  int tid = threadIdx.x;
  int base = blockIdx.x*64;
  int wv = tid>>6, lane = tid&63, quad = lane>>4, l15 = lane&15;
  if (tid < 64) Sedge[tid] = 0.f;
  if (tid < 4) part[tid] = 0.f;
  // attr slices (s=8..15): per-lane-source gload
  {
    int g = wv*64 + lane;
    int p = g>>3, hi = (g>>2)&1, cs = g&3;
    int n = p*2 + hi, cc = cs ^ (p&3);
    const short* srcb = attrS + (size_t)(base+n)*256 + cc*8;
    #pragma unroll
    for (int s=8; s<16; s++)
      gload_lds16(srcb + (s-8)*32, (char*)Bls + (size_t)s*4096 + wv*1024);
  }
  // xr*xc slices (s=0..7), bf16 inputs
  {
    int g = tid;
    int p = g>>3, hi = (g>>2)&1, cs = g&3;
    int n = p*2 + hi, cc = cs ^ (p&3);
    int rr = ei[base+n], rc = ei[E+base+n];
    const short* xr = xF + (size_t)rr*256 + cc*8;
    const short* xc = xF + (size_t)rc*256 + cc*8;
    #pragma unroll
    for (int s=0; s<8; s++){
      bf16x8 va = *(const bf16x8*)(xr + s*32);
      bf16x8 vb = *(const bf16x8*)(xc + s*32);
      float f[8];
      #pragma unroll
      for (int j=0;j<8;j++) f[j] = bf2f(va[j])*bf2f(vb[j]);
      *(uint4*)(Bls + (size_t)s*2048 + g*8) = pack8(f);
    }
  }
  __syncthreads();
  // ---- L1: 16 barrier-free K-slices; M=256, N=64 ----
  f32x4 acc[4][4];
  #pragma unroll
  for (int mt=0;mt<4;mt++) for (int nt=0;nt<4;nt++) acc[mt][nt] = (f32x4)0.f;
  #pragma unroll
  for (int s=0; s<16; s++){
    bf16x8 a[4], b[4];
    #pragma unroll
    for (int mt=0;mt<4;mt++)
      a[mt] = *(const bf16x8*)(W1t + (size_t)((wv*4+mt)*16 + l15)*512 + s*32 + quad*8);
    #pragma unroll
    for (int nt=0;nt<4;nt++)
      b[nt] = *(const bf16x8*)(Bls + (size_t)s*2048 + frag_off(nt*16 + l15, quad));
    #pragma unroll
    for (int mt=0;mt<4;mt++)
      #pragma unroll
      for (int nt=0;nt<4;nt++)
        acc[mt][nt] = MFMA16(a[mt], b[nt], acc[mt][nt]);
  }
  __syncthreads();   // all waves done reading Bls; T aliases it
  #pragma unroll
  for (int mt=0;mt<4;mt++){
    int f0 = (wv*4+mt)*16 + quad*4;
    float4 bb = *(const float4*)(ob1 + f0);
    int c = f0 >> 3, off = (quad&1)*4;
    #pragma unroll
    for (int nt=0;nt<4;nt++){
      int n = nt*16 + l15;
      float v0 = fmaxf(acc[mt][nt][0]+bb.x,0.f), v1 = fmaxf(acc[mt][nt][1]+bb.y,0.f);
      float v2 = fmaxf(acc[mt][nt][2]+bb.z,0.f), v3 = fmaxf(acc[mt][nt][3]+bb.w,0.f);
      uint2 v; v.x = pack2(v0,v1); v.y = pack2(v2,v3);
      *(uint2*)(T + n*256 + ((c ^ (n&7))*8) + off) = v;
    }
  }
  __syncthreads();
  // ---- L2: 8 barrier-free K-slices; M=128, N=64; A direct (L2-hot) ----
  f32x4 acc2[2][4];
  #pragma unroll
  for (int mt=0;mt<2;mt++) for (int nt=0;nt<4;nt++) acc2[mt][nt] = (f32x4)0.f;
  #pragma unroll
  for (int s=0; s<8; s++){
    bf16x8 a[2], b[4];
    #pragma unroll
    for (int mt=0;mt<2;mt++)
      a[mt] = *(const bf16x8*)(W2t + (size_t)((wv*2+mt)*16 + l15)*256 + s*32 + quad*8);
    #pragma unroll
    for (int nt=0;nt<4;nt++){
      int n = nt*16 + l15; int cc = s*4 + quad;
      b[nt] = *(const bf16x8*)(T + n*256 + ((cc ^ (n&7))*8));
    }
    #pragma unroll
    for (int mt=0;mt<2;mt++)
      #pragma unroll
      for (int nt=0;nt<4;nt++)
        acc2[mt][nt] = MFMA16(a[mt], b[nt], acc2[mt][nt]);
  }
  // ---- L3 dot + cross-wave per-edge reduce ----
  float4 b2v[2], w3v[2];
  #pragma unroll
  for (int mt=0;mt<2;mt++){
    int f0 = (wv*2+mt)*16 + quad*4;
    b2v[mt] = *(const float4*)(ob2 + f0);
    w3v[mt] = *(const float4*)(W3 + f0);
  }
  #pragma unroll
  for (int nt=0;nt<4;nt++){
    float p = 0.f;
    #pragma unroll
    for (int mt=0;mt<2;mt++){
      p += fmaxf(acc2[mt][nt][0]+b2v[mt].x,0.f)*w3v[mt].x;
      p += fmaxf(acc2[mt][nt][1]+b2v[mt].y,0.f)*w3v[mt].y;
      p += fmaxf(acc2[mt][nt][2]+b2v[mt].z,0.f)*w3v[mt].z;
      p += fmaxf(acc2[mt][nt][3]+b2v[mt].w,0.f)*w3v[mt].w;
    }
    p += __shfl_xor(p, 16);
    p += __shfl_xor(p, 32);
    if (lane < 16) atomicAdd(&Sedge[nt*16 + l15], p);
  }
  __syncthreads();
  // ---- loss + per-block graph reduction (block spans <=2 graphs) ----
  int gbase = n2g[ei[base]];
  if (tid < 64){
    int e = base + tid;
    float sv = Sedge[tid] + ob3[0] + dnoise[e];
    float l = 0.5f*sv*sv;
    int g = n2g[ei[e]] - gbase;     // in {0,1}
    atomicAdd(&part[g & 3], l);
  }
  __syncthreads();
  if (tid < 2 && (gbase + tid) < G)
    atomicAdd(&out[gbase + tid], part[tid]);
}

// =========================== host ===========================
static inline size_t alignup(size_t v){ return (v + 255) & ~(size_t)255; }

extern "C" void kernel_launch(void* const* d_in, const int* in_sizes, int n_in,
                              void* d_out, int out_size, void* d_ws, size_t ws_size,
                              hipStream_t stream) {
  const int*   at    = (const int*)  d_in[0];
  const int*   ei    = (const int*)  d_in[1];
  const int*   etype = (const int*)  d_in[2];
  const int*   n2g   = (const int*)  d_in[3];
  const int*   nl    = (const int*)  d_in[4];
  const float* pos   = (const float*)d_in[5];
  const float* dnoi  = (const float*)d_in[6];
  const float* sig   = (const float*)d_in[7];
  const float* nemb  = (const float*)d_in[8];
  const float* eemb  = (const float*)d_in[9];
  const float* inW1  = (const float*)d_in[10];
  const float* inb1  = (const float*)d_in[11];
  const float* inW2  = (const float*)d_in[12];
  const float* inb2  = (const float*)d_in[13];
  const float* gW1   = (const float*)d_in[14];
  const float* gb1   = (const float*)d_in[15];
  const float* gW2   = (const float*)d_in[16];
  const float* gb2   = (const float*)d_in[17];
  const float* oW1   = (const float*)d_in[18];
  const float* ob1   = (const float*)d_in[19];
  const float* oW2   = (const float*)d_in[20];
  const float* ob2   = (const float*)d_in[21];
  const float* oW3   = (const float*)d_in[22];
  const float* ob3   = (const float*)d_in[23];
  float* out = (float*)d_out;

  const int N = in_sizes[0];
  const int E = in_sizes[2];
  const int G = in_sizes[4];
  const int H = 256;

  char* w = (char*)d_ws;
  size_t off = 0;
  size_t o_attr  = off; off = alignup(off + (size_t)E*H*2);
  size_t o_xF    = off; off = alignup(off + (size_t)N*H*2);
  size_t o_pd    = off; off = alignup(off + (size_t)E*4);
  size_t o_cnt   = off; off = alignup(off + (size_t)N*4);
  size_t o_inl   = off; off = alignup(off + (size_t)N*8*4);
  size_t o_w2t   = off; off = alignup(off + (size_t)H*H*2);
  size_t o_gw1t  = off; off = alignup(off + (size_t)4*H*H*2);
  size_t o_gw2t  = off; off = alignup(off + (size_t)4*H*H*2);
  size_t o_ow1t  = off; off = alignup(off + (size_t)H*2*H*2);
  size_t o_ow2t  = off; off = alignup(off + (size_t)(H/2)*H*2);
  (void)ws_size; (void)n_in; (void)out_size;

  short* attrS = (short*)(w + o_attr);
  short* xF    = (short*)(w + o_xF);
  float* pd    = (float*)(w + o_pd);
  int*   cnt   = (int*)  (w + o_cnt);
  int*   inl   = (int*)  (w + o_inl);
  short* w2t   = (short*)(w + o_w2t);
  short* gw1t  = (short*)(w + o_gw1t);
  short* gw2t  = (short*)(w + o_gw2t);
  short* ow1t  = (short*)(w + o_ow1t);
  short* ow2t  = (short*)(w + o_ow2t);

  hipMemsetAsync(cnt, 0, (size_t)N*4, stream);
  hipMemsetAsync(out, 0, (size_t)G*4, stream);

  k_cvtAll<<<368, 256, 0, stream>>>(inW2, gW1, gW2, oW1, oW2,
                                    w2t, gw1t, gw2t, ow1t, ow2t);

  k_pre<<<(E+255)/256, 256, 0, stream>>>(ei, n2g, nl, sig, pos, dnoi, E, pd, cnt, inl);
  k_attr<<<E/64, 256, 0, stream>>>(pd, inW1, inb1, w2t, inb2, etype, eemb, attrS, E);

  k_conv4<<<G, 512, 0, stream>>>(at, nemb, attrS, ei, cnt, inl,
                                 gw1t, gb1, gw2t, gb2, xF);

  k_head<<<E/64, 256, 0, stream>>>(xF, attrS, ei, ow1t, ob1, ow2t, ob2,
                                   oW3, ob3, dnoi, n2g, out, E, G);
}

// Round 18
// 503.191 us; speedup vs baseline: 1.1807x; 1.0076x over previous
//
#include <hip/hip_runtime.h>
#include <math.h>

typedef unsigned int u32;
typedef __attribute__((ext_vector_type(8))) short bf16x8;
typedef __attribute__((ext_vector_type(4))) float f32x4;

#define MFMA16(a,b,c) __builtin_amdgcn_mfma_f32_16x16x32_bf16(a,b,c,0,0,0)

// ---------- bf16 helpers ----------
__device__ inline u32 bf16r(float x){
  u32 u = __float_as_uint(x);
  return (u + 0x7fffu + ((u >> 16) & 1u)) >> 16;
}
__device__ inline u32 pack2(float a, float b){ return bf16r(a) | (bf16r(b) << 16); }
__device__ inline uint4 pack8(const float* f){
  uint4 v; v.x = pack2(f[0],f[1]); v.y = pack2(f[2],f[3]);
  v.z = pack2(f[4],f[5]); v.w = pack2(f[6],f[7]); return v;
}
__device__ inline float bf2f(short s){ return __uint_as_float(((u32)(unsigned short)s) << 16); }

// async global->LDS, 16B/lane; dest = wave-uniform base + lane*16 (src per-lane OK)
__device__ __forceinline__ void gload_lds16(const void* g, void* l){
  __builtin_amdgcn_global_load_lds((const __attribute__((address_space(1))) unsigned int*)g,
                                   (__attribute__((address_space(3))) unsigned int*)l,
                                   16, 0, 0);
}

// LDS fragment offset (shorts) in paired-macro-row granule layout
__device__ __forceinline__ int frag_off(int f, int quad){
  return (f>>1)*64 + (f&1)*32 + ((quad ^ ((f>>1)&3))*8);
}

// bf16-row granule swizzle: row = 32 granules x 8 shorts; mixes ch (=g>>1) and row into banks
__device__ __forceinline__ int xg2(int g, int r){ return g ^ ((r ^ (g>>1)) & 7); }

// ---------- merged weight converter: f32 [K][Nf] -> bf16 row-major [Nf][K] ----------
__global__ void k_cvtAll(const float* __restrict__ inW2, const float* __restrict__ gW1,
                         const float* __restrict__ gW2, const float* __restrict__ oW1,
                         const float* __restrict__ oW2,
                         short* __restrict__ w2t, short* __restrict__ gw1t,
                         short* __restrict__ gw2t, short* __restrict__ ow1t,
                         short* __restrict__ ow2t){
  int gidx = blockIdx.x*256 + threadIdx.x;
  const float* src; short* dst; int t, K8, Nf;
  if (gidx < 8192)      { src = inW2; dst = w2t; t = gidx; K8 = 32; Nf = 256; }
  else if (gidx < 40960){ int r = gidx-8192;  int c = r>>13; t = r&8191;
                          src = gW1 + (size_t)c*65536; dst = gw1t + (size_t)c*65536; K8 = 32; Nf = 256; }
  else if (gidx < 73728){ int r = gidx-40960; int c = r>>13; t = r&8191;
                          src = gW2 + (size_t)c*65536; dst = gw2t + (size_t)c*65536; K8 = 32; Nf = 256; }
  else if (gidx < 90112){ t = gidx-73728; src = oW1; dst = ow1t; K8 = 64; Nf = 256; }
  else if (gidx < 94208){ t = gidx-90112; src = oW2; dst = ow2t; K8 = 32; Nf = 128; }
  else return;
  int f = t / K8, c = t - f*K8;
  float v[8];
  #pragma unroll
  for (int j=0;j<8;j++) v[j] = src[(size_t)(c*8+j)*Nf + f];
  ((uint4*)dst)[t] = pack8(v);
}

// ---------- per-edge scalars + CSR in-edge lists ----------
__global__ void k_pre(const int* __restrict__ ei, const int* __restrict__ n2g,
                      const int* __restrict__ nl, const float* __restrict__ sigmas,
                      const float* __restrict__ pos, const float* __restrict__ dn, int E,
                      float* __restrict__ pd, int* __restrict__ cnt, int* __restrict__ inlist){
  int e = blockIdx.x*256 + threadIdx.x;
  if (e >= E) return;
  int r = ei[e], c = ei[E+e];
  float sg = sigmas[nl[n2g[r]]];
  float dx = pos[3*r]-pos[3*c], dy = pos[3*r+1]-pos[3*c+1], dz = pos[3*r+2]-pos[3*c+2];
  float d = sqrtf(dx*dx + dy*dy + dz*dz);
  pd[e] = d + dn[e]*sg;
  int slot = atomicAdd(&cnt[c], 1);
  if (slot < 8) inlist[c*8 + slot] = e;
}

// ---------- edge_attr: barrier-free, no LDS. B computed in registers ----------
__global__ __launch_bounds__(256) void k_attr(
    const float* __restrict__ pd, const float* __restrict__ W1, const float* __restrict__ b1,
    const short* __restrict__ W2t, const float* __restrict__ b2,
    const int* __restrict__ etype, const float* __restrict__ eemb,
    short* __restrict__ attr, int E)
{
  int tid = threadIdx.x;
  int base = blockIdx.x*64;
  int wv = tid>>6, lane = tid&63, quad = lane>>4, l15 = lane&15;
  float pdv[4];
  #pragma unroll
  for (int nt=0;nt<4;nt++) pdv[nt] = pd[base + nt*16 + l15];
  f32x4 acc[4][4];
  #pragma unroll
  for (int mt=0;mt<4;mt++) for (int nt=0;nt<4;nt++) acc[mt][nt] = (f32x4)0.f;
  #pragma unroll
  for (int s=0; s<8; s++){
    int k0 = s*32 + quad*8;
    float4 w1a = *(const float4*)(W1 + k0), w1b = *(const float4*)(W1 + k0 + 4);
    float4 b1a = *(const float4*)(b1 + k0), b1b = *(const float4*)(b1 + k0 + 4);
    bf16x8 a[4], b[4];
    #pragma unroll
    for (int mt=0;mt<4;mt++){
      int f = (wv*4+mt)*16 + l15;
      a[mt] = *(const bf16x8*)(W2t + (size_t)f*256 + k0);
    }
    #pragma unroll
    for (int nt=0;nt<4;nt++){
      float p = pdv[nt];
      float f[8] = {fmaxf(p*w1a.x+b1a.x,0.f), fmaxf(p*w1a.y+b1a.y,0.f),
                    fmaxf(p*w1a.z+b1a.z,0.f), fmaxf(p*w1a.w+b1a.w,0.f),
                    fmaxf(p*w1b.x+b1b.x,0.f), fmaxf(p*w1b.y+b1b.y,0.f),
                    fmaxf(p*w1b.z+b1b.z,0.f), fmaxf(p*w1b.w+b1b.w,0.f)};
      uint4 u = pack8(f);
      b[nt] = *(bf16x8*)&u;
    }
    #pragma unroll
    for (int mt=0;mt<4;mt++)
      #pragma unroll
      for (int nt=0;nt<4;nt++)
        acc[mt][nt] = MFMA16(a[mt], b[nt], acc[mt][nt]);
  }
  #pragma unroll
  for (int nt=0;nt<4;nt++){
    int e = base + nt*16 + l15;
    int et = etype[e];
    #pragma unroll
    for (int mt=0;mt<4;mt++){
      int f0 = (wv*4+mt)*16 + quad*4;
      float4 bb = *(const float4*)(b2 + f0);
      float4 em = *(const float4*)(eemb + (size_t)et*256 + f0);
      float v0 = (acc[mt][nt][0]+bb.x)*em.x, v1 = (acc[mt][nt][1]+bb.y)*em.y;
      float v2 = (acc[mt][nt][2]+bb.z)*em.z, v3 = (acc[mt][nt][3]+bb.w)*em.w;
      uint2 v; v.x = pack2(v0,v1); v.y = pack2(v2,v3);
      *(uint2*)(attr + (size_t)e*256 + f0) = v;
    }
  }
}

// ---------- per-graph fused 4-conv kernel, 512 threads, bf16 x-state, 48 KB -> 3 blocks/CU ----------
__global__ __launch_bounds__(512,3) void k_conv4(
    const int* __restrict__ at, const float* __restrict__ nemb,
    const short* __restrict__ attrS, const int* __restrict__ ei,
    const int* __restrict__ cnt, const int* __restrict__ inlist,
    const short* __restrict__ gw1t, const float* __restrict__ gb1,
    const short* __restrict__ gw2t, const float* __restrict__ gb2,
    short* __restrict__ xF)
{
  __shared__ short xls[32*256];       // 16 KB bf16 state
  __shared__ uint4 AlsV[32*32];       // 16 KB
  __shared__ uint4 T1V [32*32];       // 16 KB
  short* Als = (short*)AlsV;
  short* T1  = (short*)T1V;
  int tid = threadIdx.x;
  int nbase = blockIdx.x*32;
  int wv = tid>>6, lane = tid&63, quad = lane>>4, l15 = lane&15;
  int jl = tid>>4, ch = tid&15;       // 16 threads/node, 16 feats each
  // ---- topology: fully unrolled, constant-indexed ----
  int deg;
  int eid[8], rl[8];
  {
    int j = nbase + jl;
    deg = min(cnt[j], 8);
    #pragma unroll
    for (int s=0;s<8;s++){
      int e = (s < deg) ? inlist[j*8 + s] : 0;
      eid[s] = e;
      rl[s]  = (s < deg) ? (ei[e] - nbase) : 0;
    }
  }
  // ---- init xls (bf16) from node_emb[at] ----
  {
    int a = at[nbase + jl];
    const float* src = nemb + (size_t)a*256 + ch*16;
    float f[16];
    #pragma unroll
    for (int q=0;q<4;q++){
      float4 v = *(const float4*)(src + q*4);
      f[q*4]=v.x; f[q*4+1]=v.y; f[q*4+2]=v.z; f[q*4+3]=v.w;
    }
    *(uint4*)(xls + jl*256 + xg2(ch*2,   jl)*8) = pack8(f);
    *(uint4*)(xls + jl*256 + xg2(ch*2+1, jl)*8) = pack8(f+8);
  }
  __syncthreads();
  for (int c=0; c<4; c++){
    const short* W1t = gw1t + (size_t)c*65536;
    const short* W2t = gw2t + (size_t)c*65536;
    const float* b1 = gb1 + c*256;
    const float* b2 = gb2 + c*256;
    // ---- gather staging into Als: hin[j] = x[j] + sum relu(x[r]+attr[e]) ----
    {
      float f[16];
      {
        bf16x8 v0 = *(const bf16x8*)(xls + jl*256 + xg2(ch*2,   jl)*8);
        bf16x8 v1 = *(const bf16x8*)(xls + jl*256 + xg2(ch*2+1, jl)*8);
        #pragma unroll
        for (int j=0;j<8;j++){ f[j]=bf2f(v0[j]); f[8+j]=bf2f(v1[j]); }
      }
      #pragma unroll
      for (int s=0; s<8; s++){
        if (s < deg){
          int r = rl[s];
          bf16x8 x0 = *(const bf16x8*)(xls + r*256 + xg2(ch*2,   r)*8);
          bf16x8 x1 = *(const bf16x8*)(xls + r*256 + xg2(ch*2+1, r)*8);
          const short* ar = attrS + (size_t)eid[s]*256 + ch*16;
          bf16x8 a0 = *(const bf16x8*)(ar);
          bf16x8 a1 = *(const bf16x8*)(ar + 8);
          #pragma unroll
          for (int j=0;j<8;j++){
            f[j]   += fmaxf(bf2f(x0[j]) + bf2f(a0[j]), 0.f);
            f[8+j] += fmaxf(bf2f(x1[j]) + bf2f(a1[j]), 0.f);
          }
        }
      }
      #pragma unroll
      for (int qq=0;qq<2;qq++){
        int cc = ch*2 + qq;
        *(uint4*)(Als + jl*256 + ((cc ^ (jl&7))*8)) = pack8(f + qq*8);
      }
    }
    __syncthreads();
    // ---- GEMM1: M=256 (8 waves x 32 feats), N=32, K=256; A direct from L2 ----
    f32x4 acc[2][2];
    #pragma unroll
    for (int mt=0;mt<2;mt++) for (int nt=0;nt<2;nt++) acc[mt][nt] = (f32x4)0.f;
    #pragma unroll
    for (int s=0; s<8; s++){
      bf16x8 a[2], b[2];
      #pragma unroll
      for (int mt=0;mt<2;mt++)
        a[mt] = *(const bf16x8*)(W1t + (size_t)((wv*2+mt)*16 + l15)*256 + s*32 + quad*8);
      #pragma unroll
      for (int nt=0;nt<2;nt++){
        int n = nt*16 + l15; int cc = s*4 + quad;
        b[nt] = *(const bf16x8*)(Als + n*256 + ((cc ^ (n&7))*8));
      }
      #pragma unroll
      for (int mt=0;mt<2;mt++)
        #pragma unroll
        for (int nt=0;nt<2;nt++)
          acc[mt][nt] = MFMA16(a[mt], b[nt], acc[mt][nt]);
    }
    // T1 separate buffer: write immediately (register-dependent only)
    #pragma unroll
    for (int mt=0;mt<2;mt++){
      int f0 = (wv*2+mt)*16 + quad*4;
      float4 bb = *(const float4*)(b1 + f0);
      int cg = f0 >> 3, off = (quad&1)*4;
      #pragma unroll
      for (int nt=0;nt<2;nt++){
        int n = nt*16 + l15;
        float v0 = fmaxf(acc[mt][nt][0]+bb.x,0.f), v1 = fmaxf(acc[mt][nt][1]+bb.y,0.f);
        float v2 = fmaxf(acc[mt][nt][2]+bb.z,0.f), v3 = fmaxf(acc[mt][nt][3]+bb.w,0.f);
        uint2 v; v.x = pack2(v0,v1); v.y = pack2(v2,v3);
        *(uint2*)(T1 + n*256 + ((cg ^ (n&7))*8) + off) = v;
      }
    }
    __syncthreads();
    // ---- GEMM2 ----
    f32x4 acc2[2][2];
    #pragma unroll
    for (int mt=0;mt<2;mt++) for (int nt=0;nt<2;nt++) acc2[mt][nt] = (f32x4)0.f;
    #pragma unroll
    for (int s=0; s<8; s++){
      bf16x8 a[2], b[2];
      #pragma unroll
      for (int mt=0;mt<2;mt++)
        a[mt] = *(const bf16x8*)(W2t + (size_t)((wv*2+mt)*16 + l15)*256 + s*32 + quad*8);
      #pragma unroll
      for (int nt=0;nt<2;nt++){
        int n = nt*16 + l15; int cc = s*4 + quad;
        b[nt] = *(const bf16x8*)(T1 + n*256 + ((cc ^ (n&7))*8));
      }
      #pragma unroll
      for (int mt=0;mt<2;mt++)
        #pragma unroll
        for (int nt=0;nt<2;nt++)
          acc2[mt][nt] = MFMA16(a[mt], b[nt], acc2[mt][nt]);
    }
    // ---- residual update into xls (bf16 RMW; relu for c<3) ----
    #pragma unroll
    for (int mt=0;mt<2;mt++){
      int f0 = (wv*2+mt)*16 + quad*4;
      float4 bb = *(const float4*)(b2 + f0);
      int g2 = f0 >> 3, half = (quad&1)*4;
      #pragma unroll
      for (int nt=0;nt<2;nt++){
        int n = nt*16 + l15;
        short* px = xls + n*256 + xg2(g2, n)*8 + half;
        uint2 old = *(uint2*)px;
        float o0 = __uint_as_float(old.x<<16), o1 = __uint_as_float(old.x&0xffff0000u);
        float o2 = __uint_as_float(old.y<<16), o3 = __uint_as_float(old.y&0xffff0000u);
        float h0 = acc2[mt][nt][0]+bb.x, h1 = acc2[mt][nt][1]+bb.y;
        float h2 = acc2[mt][nt][2]+bb.z, h3 = acc2[mt][nt][3]+bb.w;
        if (c < 3){ h0=fmaxf(h0,0.f); h1=fmaxf(h1,0.f); h2=fmaxf(h2,0.f); h3=fmaxf(h3,0.f); }
        uint2 v; v.x = pack2(o0+h0, o1+h1); v.y = pack2(o2+h2, o3+h3);
        *(uint2*)px = v;
      }
    }
    __syncthreads();
  }
  // ---- writeout xF (bf16, row-major): pure copy ----
  {
    uint4 v0 = *(const uint4*)(xls + jl*256 + xg2(ch*2,   jl)*8);
    uint4 v1 = *(const uint4*)(xls + jl*256 + xg2(ch*2+1, jl)*8);
    *(uint4*)(xF + (size_t)(nbase+jl)*256 + ch*16)     = v0;
    *(uint4*)(xF + (size_t)(nbase+jl)*256 + ch*16 + 8) = v1;
  }
}

// ---------- fully fused head, 512 threads: L1 -> T -> L2 -> L3 -> loss ----------
// 64 edges/block; 8 waves; 2 blocks/CU; 2 global atomics/block
__global__ __launch_bounds__(512,2) void k_head(
    const short* __restrict__ xF, const short* __restrict__ attrS,
    const int* __restrict__ ei,
    const short* __restrict__ W1t, const float* __restrict__ ob1,
    const short* __restrict__ W2t, const float* __restrict__ ob2,
    const float* __restrict__ W3, const float* __restrict__ ob3,
    const float* __restrict__ dnoise, const int* __restrict__ n2g,
    float* __restrict__ out, int E, int G)
{
  __shared__ uint4 BlsV[16*256];   // 64 KB; T (32 KB) aliases after L1
  __shared__ float Sedge[64];
  __shared__ float part[4];
  short* Bls = (short*)BlsV;
  short* T   = (short*)BlsV;
  int tid = threadIdx.x;
  int base = blockIdx.x*64;
  int wv = tid>>6, lane = tid&63, quad = lane>>4, l15 = lane&15;
  if (tid < 64) Sedge[tid] = 0.f;
  if (tid < 4) part[tid] = 0.f;
  int g8 = tid & 255, sh = tid >> 8, w4 = g8 >> 6;
  // attr slices (s=8..15): 2 slices/pass x 4 passes
  {
    int p = g8>>3, hi = (g8>>2)&1, cs = g8&3;
    int n = p*2 + hi, cc = cs ^ (p&3);
    const short* srcb = attrS + (size_t)(base+n)*256 + cc*8;
    #pragma unroll
    for (int i=0;i<4;i++){
      int s = 8 + i*2 + sh;
      gload_lds16(srcb + (s-8)*32, (char*)BlsV + (size_t)s*4096 + w4*1024);
    }
  }
  // xr*xc slices (s=0..7): each thread-half does 4 slices
  {
    int p = g8>>3, hi = (g8>>2)&1, cs = g8&3;
    int n = p*2 + hi, cc = cs ^ (p&3);
    int rr = ei[base+n], rc = ei[E+base+n];
    const short* xr = xF + (size_t)rr*256 + cc*8;
    const short* xc = xF + (size_t)rc*256 + cc*8;
    #pragma unroll
    for (int i=0;i<4;i++){
      int s = sh*4 + i;
      bf16x8 va = *(const bf16x8*)(xr + s*32);
      bf16x8 vb = *(const bf16x8*)(xc + s*32);
      float f[8];
      #pragma unroll
      for (int j=0;j<8;j++) f[j] = bf2f(va[j])*bf2f(vb[j]);
      *(uint4*)(Bls + (size_t)s*2048 + g8*8) = pack8(f);
    }
  }
  __syncthreads();
  // ---- L1: 16 barrier-free K-slices; M=256 (8 waves x 32 feats), N=64 ----
  f32x4 acc[2][4];
  #pragma unroll
  for (int mt=0;mt<2;mt++) for (int nt=0;nt<4;nt++) acc[mt][nt] = (f32x4)0.f;
  #pragma unroll
  for (int s=0; s<16; s++){
    bf16x8 a[2], b[4];
    #pragma unroll
    for (int mt=0;mt<2;mt++)
      a[mt] = *(const bf16x8*)(W1t + (size_t)((wv*2+mt)*16 + l15)*512 + s*32 + quad*8);
    #pragma unroll
    for (int nt=0;nt<4;nt++)
      b[nt] = *(const bf16x8*)(Bls + (size_t)s*2048 + frag_off(nt*16 + l15, quad));
    #pragma unroll
    for (int mt=0;mt<2;mt++)
      #pragma unroll
      for (int nt=0;nt<4;nt++)
        acc[mt][nt] = MFMA16(a[mt], b[nt], acc[mt][nt]);
  }
  __syncthreads();   // all waves done reading Bls; T aliases it
  #pragma unroll
  for (int mt=0;mt<2;mt++){
    int f0 = (wv*2+mt)*16 + quad*4;
    float4 bb = *(const float4*)(ob1 + f0);
    int c = f0 >> 3, off = (quad&1)*4;
    #pragma unroll
    for (int nt=0;nt<4;nt++){
      int n = nt*16 + l15;
      float v0 = fmaxf(acc[mt][nt][0]+bb.x,0.f), v1 = fmaxf(acc[mt][nt][1]+bb.y,0.f);
      float v2 = fmaxf(acc[mt][nt][2]+bb.z,0.f), v3 = fmaxf(acc[mt][nt][3]+bb.w,0.f);
      uint2 v; v.x = pack2(v0,v1); v.y = pack2(v2,v3);
      *(uint2*)(T + n*256 + ((c ^ (n&7))*8) + off) = v;
    }
  }
  __syncthreads();
  // ---- L2: 8 barrier-free K-slices; M=128 (8 waves x 16 feats), N=64; A direct ----
  f32x4 acc2[4];
  #pragma unroll
  for (int nt=0;nt<4;nt++) acc2[nt] = (f32x4)0.f;
  #pragma unroll
  for (int s=0; s<8; s++){
    bf16x8 a = *(const bf16x8*)(W2t + (size_t)(wv*16 + l15)*256 + s*32 + quad*8);
    #pragma unroll
    for (int nt=0;nt<4;nt++){
      int n = nt*16 + l15; int cc = s*4 + quad;
      bf16x8 b = *(const bf16x8*)(T + n*256 + ((cc ^ (n&7))*8));
      acc2[nt] = MFMA16(a, b, acc2[nt]);
    }
  }
  // ---- L3 dot + cross-wave per-edge reduce ----
  {
    int f0 = wv*16 + quad*4;
    float4 bb = *(const float4*)(ob2 + f0);
    float4 w3 = *(const float4*)(W3 + f0);
    #pragma unroll
    for (int nt=0;nt<4;nt++){
      float p = fmaxf(acc2[nt][0]+bb.x,0.f)*w3.x + fmaxf(acc2[nt][1]+bb.y,0.f)*w3.y
              + fmaxf(acc2[nt][2]+bb.z,0.f)*w3.z + fmaxf(acc2[nt][3]+bb.w,0.f)*w3.w;
      p += __shfl_xor(p, 16);
      p += __shfl_xor(p, 32);
      if (lane < 16) atomicAdd(&Sedge[nt*16 + l15], p);
    }
  }
  __syncthreads();
  // ---- loss + per-block graph reduction (block spans <=2 graphs) ----
  int gbase = n2g[ei[base]];
  if (tid < 64){
    int e = base + tid;
    float sv = Sedge[tid] + ob3[0] + dnoise[e];
    float l = 0.5f*sv*sv;
    int g = n2g[ei[e]] - gbase;     // in {0,1}
    atomicAdd(&part[g & 3], l);
  }
  __syncthreads();
  if (tid < 2 && (gbase + tid) < G)
    atomicAdd(&out[gbase + tid], part[tid]);
}

// =========================== host ===========================
static inline size_t alignup(size_t v){ return (v + 255) & ~(size_t)255; }

extern "C" void kernel_launch(void* const* d_in, const int* in_sizes, int n_in,
                              void* d_out, int out_size, void* d_ws, size_t ws_size,
                              hipStream_t stream) {
  const int*   at    = (const int*)  d_in[0];
  const int*   ei    = (const int*)  d_in[1];
  const int*   etype = (const int*)  d_in[2];
  const int*   n2g   = (const int*)  d_in[3];
  const int*   nl    = (const int*)  d_in[4];
  const float* pos   = (const float*)d_in[5];
  const float* dnoi  = (const float*)d_in[6];
  const float* sig   = (const float*)d_in[7];
  const float* nemb  = (const float*)d_in[8];
  const float* eemb  = (const float*)d_in[9];
  const float* inW1  = (const float*)d_in[10];
  const float* inb1  = (const float*)d_in[11];
  const float* inW2  = (const float*)d_in[12];
  const float* inb2  = (const float*)d_in[13];
  const float* gW1   = (const float*)d_in[14];
  const float* gb1   = (const float*)d_in[15];
  const float* gW2   = (const float*)d_in[16];
  const float* gb2   = (const float*)d_in[17];
  const float* oW1   = (const float*)d_in[18];
  const float* ob1   = (const float*)d_in[19];
  const float* oW2   = (const float*)d_in[20];
  const float* ob2   = (const float*)d_in[21];
  const float* oW3   = (const float*)d_in[22];
  const float* ob3   = (const float*)d_in[23];
  float* out = (float*)d_out;

  const int N = in_sizes[0];
  const int E = in_sizes[2];
  const int G = in_sizes[4];
  const int H = 256;

  char* w = (char*)d_ws;
  size_t off = 0;
  size_t o_attr  = off; off = alignup(off + (size_t)E*H*2);
  size_t o_xF    = off; off = alignup(off + (size_t)N*H*2);
  size_t o_pd    = off; off = alignup(off + (size_t)E*4);
  size_t o_cnt   = off; off = alignup(off + (size_t)N*4);
  size_t o_inl   = off; off = alignup(off + (size_t)N*8*4);
  size_t o_w2t   = off; off = alignup(off + (size_t)H*H*2);
  size_t o_gw1t  = off; off = alignup(off + (size_t)4*H*H*2);
  size_t o_gw2t  = off; off = alignup(off + (size_t)4*H*H*2);
  size_t o_ow1t  = off; off = alignup(off + (size_t)H*2*H*2);
  size_t o_ow2t  = off; off = alignup(off + (size_t)(H/2)*H*2);
  (void)ws_size; (void)n_in; (void)out_size;

  short* attrS = (short*)(w + o_attr);
  short* xF    = (short*)(w + o_xF);
  float* pd    = (float*)(w + o_pd);
  int*   cnt   = (int*)  (w + o_cnt);
  int*   inl   = (int*)  (w + o_inl);
  short* w2t   = (short*)(w + o_w2t);
  short* gw1t  = (short*)(w + o_gw1t);
  short* gw2t  = (short*)(w + o_gw2t);
  short* ow1t  = (short*)(w + o_ow1t);
  short* ow2t  = (short*)(w + o_ow2t);

  hipMemsetAsync(cnt, 0, (size_t)N*4, stream);
  hipMemsetAsync(out, 0, (size_t)G*4, stream);

  k_cvtAll<<<368, 256, 0, stream>>>(inW2, gW1, gW2, oW1, oW2,
                                    w2t, gw1t, gw2t, ow1t, ow2t);

  k_pre<<<(E+255)/256, 256, 0, stream>>>(ei, n2g, nl, sig, pos, dnoi, E, pd, cnt, inl);
  k_attr<<<E/64, 256, 0, stream>>>(pd, inW1, inb1, w2t, inb2, etype, eemb, attrS, E);

  k_conv4<<<G, 512, 0, stream>>>(at, nemb, attrS, ei, cnt, inl,
                                 gw1t, gb1, gw2t, gb2, xF);

  k_head<<<E/64, 512, 0, stream>>>(xF, attrS, ei, ow1t, ob1, ow2t, ob2,
                                   oW3, ob3, dnoi, n2g, out, E, G);
}